// Round 1
// baseline (994.395 us; speedup 1.0000x reference)
//
#include <hip/hip_runtime.h>
#include <hip/hip_bf16.h>
#include <cstddef>

typedef unsigned int  u32;
typedef unsigned short u16;

#define DV 128
#define DH 128
#define DE 16
#define DO 128

// ---------- bf16 helpers (bit tricks, RNE) ----------
__device__ inline float bf_lo(u32 u){ return __uint_as_float(u << 16); }
__device__ inline float bf_hi(u32 u){ return __uint_as_float(u & 0xFFFF0000u); }
__device__ inline u32 fpack2(float a, float b){
  u32 ua = __float_as_uint(a), ub = __float_as_uint(b);
  ua += 0x7FFFu + ((ua >> 16) & 1u);
  ub += 0x7FFFu + ((ub >> 16) & 1u);
  return (ua >> 16) | (ub & 0xFFFF0000u);
}
__device__ inline u16 f2bf(float a){
  u32 ua = __float_as_uint(a); ua += 0x7FFFu + ((ua >> 16) & 1u); return (u16)(ua >> 16);
}

// ---------- CSR build ----------
__global__ void k_init(int* cnt, int n){
  int v = blockIdx.x * blockDim.x + threadIdx.x;
  if (v < n) cnt[v] = 0;
}
__global__ void k_count(const int* dst, int* cnt, int e2){
  int j = blockIdx.x * blockDim.x + threadIdx.x;
  if (j < e2) atomicAdd(&cnt[dst[j]], 1);
}
__global__ __launch_bounds__(256) void k_scan1(const int* cnt, int* partial, int* bsums, int n){
  __shared__ int lds[256];
  int t = threadIdx.x;
  int base = blockIdx.x * 1024 + t * 4;
  int v0=0,v1=0,v2=0,v3=0;
  if (base + 3 < n){ int4 q = *(const int4*)(cnt + base); v0=q.x; v1=q.y; v2=q.z; v3=q.w; }
  else {
    if (base + 0 < n) v0 = cnt[base];
    if (base + 1 < n) v1 = cnt[base+1];
    if (base + 2 < n) v2 = cnt[base+2];
  }
  v1 += v0; v2 += v1; v3 += v2;
  lds[t] = v3; __syncthreads();
  for (int off = 1; off < 256; off <<= 1){
    int x = (t >= off) ? lds[t - off] : 0;
    __syncthreads();
    lds[t] += x;
    __syncthreads();
  }
  int add = (t > 0) ? lds[t - 1] : 0;
  if (base + 3 < n){
    int4 q; q.x = v0+add; q.y = v1+add; q.z = v2+add; q.w = v3+add;
    *(int4*)(partial + base) = q;
  } else {
    if (base + 0 < n) partial[base]   = v0 + add;
    if (base + 1 < n) partial[base+1] = v1 + add;
    if (base + 2 < n) partial[base+2] = v2 + add;
  }
  if (t == 255) bsums[blockIdx.x] = lds[255];
}
__global__ void k_scan2(const int* bsums, int* bexc, int nb){
  __shared__ int lds[128];
  int t = threadIdx.x;
  lds[t] = (t < nb) ? bsums[t] : 0;
  __syncthreads();
  for (int off = 1; off < 128; off <<= 1){
    int x = (t >= off) ? lds[t - off] : 0;
    __syncthreads();
    lds[t] += x;
    __syncthreads();
  }
  if (t < nb) bexc[t] = (t > 0) ? lds[t - 1] : 0;
}
__global__ void k_scan3(const int* partial, const int* bexc, int* row_ptr, int n){
  int i = blockIdx.x * blockDim.x + threadIdx.x;
  if (i < n) row_ptr[i + 1] = partial[i] + bexc[i >> 10];
  if (i == 0) row_ptr[0] = 0;
}
__global__ void k_prep(const int* row_ptr, const int* cnt, int* fill, float* dinv, float* degf, int n){
  int v = blockIdx.x * blockDim.x + threadIdx.x;
  if (v < n){
    fill[v] = row_ptr[v];
    float c = (float)(cnt[v] + 1);   // in-degree + self-loop
    dinv[v] = rsqrtf(c);
    degf[v] = c;
  }
}
__global__ void k_scatter(const int* src, const int* dst, int* fill, int* col, int* halfi, int e2){
  int j = blockIdx.x * blockDim.x + threadIdx.x;
  if (j < e2){
    int d = dst[j];
    int pos = atomicAdd(&fill[d], 1);
    col[pos]  = src[j];
    halfi[pos] = j >> 1;   // edge_attr row index (jnp.repeat interleaves)
  }
}

// ---------- fold W_le@W_bot and biases into the h2 GEMM weight ----------
// Wfull[160][128]: rows 0..127 = W_top, 128..143 = W_le@W_bot,
// row 144 = b_le@W_bot + b_lin (picked up by deg column), 145..159 = 0
__global__ __launch_bounds__(128) void k_wcombo(const float* W_lin, const float* b_lin,
                                                const float* W_le, const float* b_le, float* Wfull){
  __shared__ float wle[DE * DH];
  int c = threadIdx.x;
  for (int i = c; i < DE * DH; i += 128) wle[i] = W_le[i];
  __syncthreads();
  float combo[DE];
  #pragma unroll
  for (int i = 0; i < DE; i++) combo[i] = 0.f;
  float bacc = b_lin[c];
  for (int k = 0; k < DH; ++k){
    float wv = W_lin[(size_t)(DH + k) * DH + c];   // W_bot[k][c]
    bacc += b_le[k] * wv;
    #pragma unroll
    for (int i = 0; i < DE; i++) combo[i] += wle[i * DH + k] * wv;
  }
  for (int r = 0; r < DH; ++r) Wfull[r * DH + c] = W_lin[r * DH + c];
  #pragma unroll
  for (int i = 0; i < DE; i++) Wfull[(DH + i) * DH + c] = combo[i];
  Wfull[144 * DH + c] = bacc;
  for (int r = 145; r < 160; ++r) Wfull[r * DH + c] = 0.f;
}

// ---------- register-tiled GEMM: [M,K] @ [K,128] -> bf16-packed out ----------
// block = 256 threads, 32 rows x 128 cols; per-thread 4x4 micro-tile
template<int K, bool RELU, bool ABF16>
__global__ __launch_bounds__(256) void k_gemm(const void* Ap, const float* W, u32* outb, int M){
  __shared__ float Ws[32][128];
  __shared__ float At[32][36];   // [k][row], padded
  int tid = threadIdx.x;
  int row0 = blockIdx.x * 32;
  int tc = tid & 31, tr = tid >> 5;
  int c0 = tc * 4, r0 = tr * 4;
  float acc[4][4];
  #pragma unroll
  for (int i = 0; i < 4; i++)
    #pragma unroll
    for (int j = 0; j < 4; j++) acc[i][j] = 0.f;
  int lr = tid >> 3;          // 0..31 A row
  int lk = (tid & 7) * 4;     // 0..28 k offset
  for (int kc = 0; kc < K; kc += 32){
    int gr = row0 + lr; if (gr > M - 1) gr = M - 1;
    if (ABF16){
      const u16* A = (const u16*)Ap;
      uint2 q = *(const uint2*)(A + (size_t)gr * K + kc + lk);
      At[lk+0][lr] = bf_lo(q.x); At[lk+1][lr] = bf_hi(q.x);
      At[lk+2][lr] = bf_lo(q.y); At[lk+3][lr] = bf_hi(q.y);
    } else {
      const float* A = (const float*)Ap;
      float4 q = *(const float4*)(A + (size_t)gr * K + kc + lk);
      At[lk+0][lr] = q.x; At[lk+1][lr] = q.y; At[lk+2][lr] = q.z; At[lk+3][lr] = q.w;
    }
    {
      int c4 = (tid & 31) * 4, kb = tid >> 5;
      #pragma unroll
      for (int p = 0; p < 4; p++){
        int kr = kb + p * 8;
        *(float4*)&Ws[kr][c4] = *(const float4*)(W + (size_t)(kc + kr) * DH + c4);
      }
    }
    __syncthreads();
    #pragma unroll
    for (int kk = 0; kk < 32; ++kk){
      float4 w = *(const float4*)&Ws[kk][c0];
      float4 a = *(const float4*)&At[kk][r0];
      acc[0][0] += a.x*w.x; acc[0][1] += a.x*w.y; acc[0][2] += a.x*w.z; acc[0][3] += a.x*w.w;
      acc[1][0] += a.y*w.x; acc[1][1] += a.y*w.y; acc[1][2] += a.y*w.z; acc[1][3] += a.y*w.w;
      acc[2][0] += a.z*w.x; acc[2][1] += a.z*w.y; acc[2][2] += a.z*w.z; acc[2][3] += a.z*w.w;
      acc[3][0] += a.w*w.x; acc[3][1] += a.w*w.y; acc[3][2] += a.w*w.z; acc[3][3] += a.w*w.w;
    }
    __syncthreads();
  }
  #pragma unroll
  for (int i = 0; i < 4; i++){
    int r = row0 + r0 + i;
    if (r < M){
      float x0 = acc[i][0], x1 = acc[i][1], x2 = acc[i][2], x3 = acc[i][3];
      if (RELU){ x0 = fmaxf(x0, 0.f); x1 = fmaxf(x1, 0.f); x2 = fmaxf(x2, 0.f); x3 = fmaxf(x3, 0.f); }
      uint2 o; o.x = fpack2(x0, x1); o.y = fpack2(x2, x3);
      *(uint2*)(outb + (size_t)r * 64 + tc * 2) = o;
    }
  }
}

// ---------- phase 1: GCN aggregate  h = relu(sum norm*xw[src] + dinv^2*xw[v] + b_gcn) ----------
__global__ __launch_bounds__(256) void k_phase1(const u32* xw_b, const int* row_ptr, const int* col,
                                                const float* dinv, const float* b_gcn, u32* h_b, int n){
  int lane = threadIdx.x & 63;
  int v = blockIdx.x * 4 + (threadIdx.x >> 6);
  if (v >= n) return;
  float dv = dinv[v];
  u32 sp = xw_b[(size_t)v * 64 + lane];
  float s0 = dv * dv;
  float ax = bf_lo(sp) * s0, ay = bf_hi(sp) * s0;
  int e0 = row_ptr[v], e1 = row_ptr[v + 1];
  for (int i = e0; i < e1; ++i){
    int s = col[i];
    float sc = dv * dinv[s];
    u32 q = xw_b[(size_t)s * 64 + lane];
    ax += sc * bf_lo(q); ay += sc * bf_hi(q);
  }
  float2 bg = *(const float2*)(b_gcn + lane * 2);
  ax = fmaxf(ax + bg.x, 0.f); ay = fmaxf(ay + bg.y, 0.f);
  h_b[(size_t)v * 64 + lane] = fpack2(ax, ay);
}

// ---------- phase 2: sum h[src] (+self) and edge_attr (+ones); emit [N,160] bf16 row ----------
__global__ __launch_bounds__(256) void k_phase2(const u32* h_b, const int* row_ptr, const int* col,
                                                const int* halfi, const float* edge_attr,
                                                const float* degf, u16* A2b, int n){
  int lane = threadIdx.x & 63;
  int v = blockIdx.x * 4 + (threadIdx.x >> 6);
  if (v >= n) return;
  u32 sp = h_b[(size_t)v * 64 + lane];     // self loop
  float ax = bf_lo(sp), ay = bf_hi(sp);
  float ae = (lane < DE) ? 1.0f : 0.0f;    // self-loop attr = ones
  int e0 = row_ptr[v], e1 = row_ptr[v + 1];
  for (int i = e0; i < e1; ++i){
    int s = col[i];
    u32 q = h_b[(size_t)s * 64 + lane];
    ax += bf_lo(q); ay += bf_hi(q);
    if (lane < DE){
      int hf = halfi[i];
      ae += edge_attr[(size_t)hf * DE + lane];
    }
  }
  u16* rowp = A2b + (size_t)v * 160;
  ((u32*)rowp)[lane] = fpack2(ax, ay);
  u16 ex;
  if (lane < DE) ex = f2bf(ae);
  else if (lane == 16) ex = f2bf(degf[v]);   // exact: small int
  else ex = 0;
  if (lane < 32) rowp[128 + lane] = ex;
}

// ---------- pooling ----------
__global__ void k_starts(const int* batch, int* start, int n, int g){
  int v = blockIdx.x * blockDim.x + threadIdx.x;
  if (v >= n) return;
  int b = batch[v];
  int prev = (v == 0) ? -1 : batch[v - 1];
  for (int q = prev + 1; q <= b; ++q) start[q] = v;
  if (v == n - 1){ for (int q = b + 1; q <= g; ++q) start[q] = n; }
}
__global__ __launch_bounds__(256) void k_pool(const u32* h2_b, const int* start, float* pooled, int n){
  __shared__ float2 red[256];
  int g = blockIdx.x;
  int s0 = start[g], s1 = start[g + 1];
  int tid = threadIdx.x;
  int cu = tid & 63, rr = tid >> 6;
  float ax = 0.f, ay = 0.f;
  for (int r = s0 + rr; r < s1; r += 4){
    u32 q = h2_b[(size_t)r * 64 + cu];
    ax += bf_lo(q); ay += bf_hi(q);
  }
  red[tid] = make_float2(ax, ay);
  __syncthreads();
  if (rr == 0){
    #pragma unroll
    for (int p = 1; p < 4; p++){ float2 o = red[cu + (p << 6)]; ax += o.x; ay += o.y; }
    int c = s1 - s0; if (c < 1) c = 1;
    float inv = 1.0f / (float)c;
    pooled[g * DH + cu * 2]     = ax * inv;
    pooled[g * DH + cu * 2 + 1] = ay * inv;
  }
}
__global__ __launch_bounds__(128) void k_final(const float* pooled, const float* W_out,
                                               const float* b_out, float* out){
  __shared__ float pl[DH];
  int g = blockIdx.x, o = threadIdx.x;
  pl[o] = pooled[g * DH + o];
  __syncthreads();
  float acc = b_out[o];
  for (int k = 0; k < DH; ++k) acc += pl[k] * W_out[k * DO + o];
  out[g * DO + o] = acc;
}

extern "C" void kernel_launch(void* const* d_in, const int* in_sizes, int n_in,
                              void* d_out, int out_size, void* d_ws, size_t ws_size,
                              hipStream_t stream){
  const float* x         = (const float*)d_in[0];
  const int*   edge_index= (const int*)  d_in[1];
  const float* edge_attr = (const float*)d_in[2];
  const int*   batch     = (const int*)  d_in[3];
  const float* W_gcn     = (const float*)d_in[4];
  const float* b_gcn     = (const float*)d_in[5];
  const float* W_le      = (const float*)d_in[6];
  const float* b_le      = (const float*)d_in[7];
  const float* W_lin     = (const float*)d_in[8];
  const float* b_lin     = (const float*)d_in[9];
  const float* W_out     = (const float*)d_in[10];
  const float* b_out     = (const float*)d_in[11];
  float* out = (float*)d_out;

  const int n  = in_sizes[0] / DV;       // 100000
  const int e2 = in_sizes[1] / 2;        // 1600000 directed edges
  const int g  = out_size / DO;          // 64
  const int* srcp = edge_index;
  const int* dstp = edge_index + e2;

  char* ws = (char*)d_ws;
  size_t off = 0;
  auto alloc = [&](size_t bytes) -> char* {
    char* p = ws + off; off = (off + bytes + 255) & ~(size_t)255; return p;
  };

  int*   cnt     = (int*)  alloc((size_t)n * 4);
  int*   row_ptr = (int*)  alloc((size_t)(n + 1) * 4);
  int*   fill    = (int*)  alloc((size_t)n * 4);
  int*   partial = (int*)  alloc((size_t)n * 4);
  int*   bsums   = (int*)  alloc(512);
  int*   bexc    = (int*)  alloc(512);
  float* dinv    = (float*)alloc((size_t)n * 4);
  float* degf    = (float*)alloc((size_t)n * 4);
  int*   startg  = (int*)  alloc((size_t)(g + 1) * 4);
  float* pooled  = (float*)alloc((size_t)g * DH * 4);
  float* Wfull   = (float*)alloc(160 * DH * 4);
  u32*   h_b     = (u32*)  alloc((size_t)n * 64 * 4);
  // region A: xw (bf16, [N,128]) later overwritten by A2 (bf16, [N,160])
  size_t szXW = (size_t)n * 64 * 4, szA2 = (size_t)n * 160 * 2;
  char* regionA = alloc(szA2 > szXW ? szA2 : szXW);
  u32* xw_b = (u32*)regionA;
  u16* A2b  = (u16*)regionA;
  // region B: col+half (CSR) later overwritten by h2 (bf16, [N,128])
  size_t szCSR = (size_t)e2 * 8, szH2 = (size_t)n * 64 * 4;
  char* regionB = alloc(szH2 > szCSR ? szH2 : szCSR);
  int* col   = (int*)regionB;
  int* halfi = (int*)(regionB + (size_t)e2 * 4);
  u32* h2_b  = (u32*)regionB;

  const int nb1024 = (n + 1023) / 1024;  // 98 (must be <= 128 for k_scan2)

  k_init   <<<(n + 255) / 256, 256, 0, stream>>>(cnt, n);
  k_count  <<<(e2 + 255) / 256, 256, 0, stream>>>(dstp, cnt, e2);
  k_scan1  <<<nb1024, 256, 0, stream>>>(cnt, partial, bsums, n);
  k_scan2  <<<1, 128, 0, stream>>>(bsums, bexc, nb1024);
  k_scan3  <<<(n + 255) / 256, 256, 0, stream>>>(partial, bexc, row_ptr, n);
  k_prep   <<<(n + 255) / 256, 256, 0, stream>>>(row_ptr, cnt, fill, dinv, degf, n);
  k_scatter<<<(e2 + 255) / 256, 256, 0, stream>>>(srcp, dstp, fill, col, halfi, e2);
  k_wcombo <<<1, 128, 0, stream>>>(W_lin, b_lin, W_le, b_le, Wfull);

  k_gemm<DV, false, false><<<(n + 31) / 32, 256, 0, stream>>>(x, W_gcn, xw_b, n);
  k_phase1 <<<(n + 3) / 4, 256, 0, stream>>>(xw_b, row_ptr, col, dinv, b_gcn, h_b, n);
  k_phase2 <<<(n + 3) / 4, 256, 0, stream>>>(h_b, row_ptr, col, halfi, edge_attr, degf, A2b, n);
  k_gemm<160, true, true><<<(n + 31) / 32, 256, 0, stream>>>(A2b, Wfull, h2_b, n);

  k_starts <<<(n + 255) / 256, 256, 0, stream>>>(batch, startg, n, g);
  k_pool   <<<g, 256, 0, stream>>>(h2_b, startg, pooled, n);
  k_final  <<<g, 128, 0, stream>>>(pooled, W_out, b_out, out);
}

// Round 2
// 777.521 us; speedup vs baseline: 1.2789x; 1.2789x over previous
//
#include <hip/hip_runtime.h>
#include <hip/hip_bf16.h>
#include <cstddef>

typedef unsigned int  u32;
typedef unsigned short u16;

#define DV 128
#define DH 128
#define DE 16
#define DO 128

// ---------- bf16 helpers (bit tricks, RNE) ----------
__device__ inline float bf_lo(u32 u){ return __uint_as_float(u << 16); }
__device__ inline float bf_hi(u32 u){ return __uint_as_float(u & 0xFFFF0000u); }
__device__ inline u32 fpack2(float a, float b){
  u32 ua = __float_as_uint(a), ub = __float_as_uint(b);
  ua += 0x7FFFu + ((ua >> 16) & 1u);
  ub += 0x7FFFu + ((ub >> 16) & 1u);
  return (ua >> 16) | (ub & 0xFFFF0000u);
}
__device__ inline u16 f2bf(float a){
  u32 ua = __float_as_uint(a); ua += 0x7FFFu + ((ua >> 16) & 1u); return (u16)(ua >> 16);
}

// ---------- CSR build ----------
__global__ void k_init(int* cnt, int n){
  int v = blockIdx.x * blockDim.x + threadIdx.x;
  if (v < n) cnt[v] = 0;
}
__global__ void k_count(const int* dst, int* cnt, int e2){
  int j = blockIdx.x * blockDim.x + threadIdx.x;
  if (j < e2) atomicAdd(&cnt[dst[j]], 1);
}
// scan of PADDED counts: pc = (cnt+3)&~3  (rows padded to multiple of 4)
__global__ __launch_bounds__(256) void k_scan1(const int* cnt, int* partial, int* bsums, int n){
  __shared__ int lds[256];
  int t = threadIdx.x;
  int base = blockIdx.x * 1024 + t * 4;
  int v0=0,v1=0,v2=0,v3=0;
  if (base + 3 < n){ int4 q = *(const int4*)(cnt + base); v0=q.x; v1=q.y; v2=q.z; v3=q.w; }
  else {
    if (base + 0 < n) v0 = cnt[base];
    if (base + 1 < n) v1 = cnt[base+1];
    if (base + 2 < n) v2 = cnt[base+2];
  }
  v0 = (v0 + 3) & ~3; v1 = (v1 + 3) & ~3; v2 = (v2 + 3) & ~3; v3 = (v3 + 3) & ~3;
  v1 += v0; v2 += v1; v3 += v2;
  lds[t] = v3; __syncthreads();
  for (int off = 1; off < 256; off <<= 1){
    int x = (t >= off) ? lds[t - off] : 0;
    __syncthreads();
    lds[t] += x;
    __syncthreads();
  }
  int add = (t > 0) ? lds[t - 1] : 0;
  if (base + 3 < n){
    int4 q; q.x = v0+add; q.y = v1+add; q.z = v2+add; q.w = v3+add;
    *(int4*)(partial + base) = q;
  } else {
    if (base + 0 < n) partial[base]   = v0 + add;
    if (base + 1 < n) partial[base+1] = v1 + add;
    if (base + 2 < n) partial[base+2] = v2 + add;
  }
  if (t == 255) bsums[blockIdx.x] = lds[255];
}
__global__ void k_scan2(const int* bsums, int* bexc, int nb){
  __shared__ int lds[128];
  int t = threadIdx.x;
  lds[t] = (t < nb) ? bsums[t] : 0;
  __syncthreads();
  for (int off = 1; off < 128; off <<= 1){
    int x = (t >= off) ? lds[t - off] : 0;
    __syncthreads();
    lds[t] += x;
    __syncthreads();
  }
  if (t < nb) bexc[t] = (t > 0) ? lds[t - 1] : 0;
}
__global__ void k_scan3(const int* partial, const int* bexc, int* row_ptr, int n){
  int i = blockIdx.x * blockDim.x + threadIdx.x;
  if (i < n) row_ptr[i + 1] = partial[i] + bexc[i >> 10];
  if (i == 0) row_ptr[0] = 0;
}
__global__ void k_prep(const int* row_ptr, const int* cnt, int* fill, float* dinv, float* degf, int n){
  int v = blockIdx.x * blockDim.x + threadIdx.x;
  if (v < n){
    fill[v] = row_ptr[v];
    float c = (float)(cnt[v] + 1);   // in-degree + self-loop
    dinv[v] = rsqrtf(c);
    degf[v] = c;
  }
}
// scatter col + reorder edge_attr into CSR slot order (bf16 packed, 32 B/edge)
__global__ void k_scatter(const int* src, const int* dst, int* fill, int* col,
                          const float* edge_attr, u32* ea_csr, int e2){
  int j = blockIdx.x * blockDim.x + threadIdx.x;
  if (j < e2){
    int d = dst[j];
    int pos = atomicAdd(&fill[d], 1);
    col[pos] = src[j];
    const float4* er = (const float4*)(edge_attr + (size_t)(j >> 1) * DE);
    float4 a = er[0], b = er[1], c = er[2], e = er[3];
    uint4 lo, hi;
    lo.x = fpack2(a.x, a.y); lo.y = fpack2(a.z, a.w);
    lo.z = fpack2(b.x, b.y); lo.w = fpack2(b.z, b.w);
    hi.x = fpack2(c.x, c.y); hi.y = fpack2(c.z, c.w);
    hi.z = fpack2(e.x, e.y); hi.w = fpack2(e.z, e.w);
    u32* p = ea_csr + (size_t)pos * 8;
    *(uint4*)p = lo; *(uint4*)(p + 4) = hi;
  }
}
// fill CSR pad slots: col -> zero-row n, ea -> zeros; also zero the gather tables' row n
__global__ void k_pad(const int* row_ptr, const int* cnt, int* col, u32* ea_csr,
                      u32* xws_zrow, u32* h_zrow, int n){
  int v = blockIdx.x * blockDim.x + threadIdx.x;
  if (v < n){
    int s = row_ptr[v] + cnt[v], e = row_ptr[v + 1];
    for (int i = s; i < e; ++i){
      col[i] = n;
      uint4 z = make_uint4(0,0,0,0);
      *(uint4*)(ea_csr + (size_t)i * 8) = z;
      *(uint4*)(ea_csr + (size_t)i * 8 + 4) = z;
    }
  }
  if (blockIdx.x == 0 && threadIdx.x < 64){
    xws_zrow[threadIdx.x] = 0u;
    h_zrow[threadIdx.x] = 0u;
  }
}

// ---------- fold W_le@W_bot and biases into the h2 GEMM weight ----------
__global__ __launch_bounds__(128) void k_wcombo(const float* W_lin, const float* b_lin,
                                                const float* W_le, const float* b_le, float* Wfull){
  __shared__ float wle[DE * DH];
  int c = threadIdx.x;
  for (int i = c; i < DE * DH; i += 128) wle[i] = W_le[i];
  __syncthreads();
  float combo[DE];
  #pragma unroll
  for (int i = 0; i < DE; i++) combo[i] = 0.f;
  float bacc = b_lin[c];
  for (int k = 0; k < DH; ++k){
    float wv = W_lin[(size_t)(DH + k) * DH + c];   // W_bot[k][c]
    bacc += b_le[k] * wv;
    #pragma unroll
    for (int i = 0; i < DE; i++) combo[i] += wle[i * DH + k] * wv;
  }
  for (int r = 0; r < DH; ++r) Wfull[r * DH + c] = W_lin[r * DH + c];
  #pragma unroll
  for (int i = 0; i < DE; i++) Wfull[(DH + i) * DH + c] = combo[i];
  Wfull[144 * DH + c] = bacc;
  for (int r = 145; r < 160; ++r) Wfull[r * DH + c] = 0.f;
}

// ---------- register-tiled GEMM: [M,K] @ [K,128] -> bf16-packed out ----------
template<int K, bool RELU, bool ABF16, bool SCALE>
__global__ __launch_bounds__(256) void k_gemm(const void* Ap, const float* W, u32* outb,
                                              const float* scale, int M){
  __shared__ float Ws[32][128];
  __shared__ float At[32][36];
  int tid = threadIdx.x;
  int row0 = blockIdx.x * 32;
  int tc = tid & 31, tr = tid >> 5;
  int c0 = tc * 4, r0 = tr * 4;
  float acc[4][4];
  #pragma unroll
  for (int i = 0; i < 4; i++)
    #pragma unroll
    for (int j = 0; j < 4; j++) acc[i][j] = 0.f;
  int lr = tid >> 3;
  int lk = (tid & 7) * 4;
  for (int kc = 0; kc < K; kc += 32){
    int gr = row0 + lr; if (gr > M - 1) gr = M - 1;
    if (ABF16){
      const u16* A = (const u16*)Ap;
      uint2 q = *(const uint2*)(A + (size_t)gr * K + kc + lk);
      At[lk+0][lr] = bf_lo(q.x); At[lk+1][lr] = bf_hi(q.x);
      At[lk+2][lr] = bf_lo(q.y); At[lk+3][lr] = bf_hi(q.y);
    } else {
      const float* A = (const float*)Ap;
      float4 q = *(const float4*)(A + (size_t)gr * K + kc + lk);
      At[lk+0][lr] = q.x; At[lk+1][lr] = q.y; At[lk+2][lr] = q.z; At[lk+3][lr] = q.w;
    }
    {
      int c4 = (tid & 31) * 4, kb = tid >> 5;
      #pragma unroll
      for (int p = 0; p < 4; p++){
        int kr = kb + p * 8;
        *(float4*)&Ws[kr][c4] = *(const float4*)(W + (size_t)(kc + kr) * DH + c4);
      }
    }
    __syncthreads();
    #pragma unroll
    for (int kk = 0; kk < 32; ++kk){
      float4 w = *(const float4*)&Ws[kk][c0];
      float4 a = *(const float4*)&At[kk][r0];
      acc[0][0] += a.x*w.x; acc[0][1] += a.x*w.y; acc[0][2] += a.x*w.z; acc[0][3] += a.x*w.w;
      acc[1][0] += a.y*w.x; acc[1][1] += a.y*w.y; acc[1][2] += a.y*w.z; acc[1][3] += a.y*w.w;
      acc[2][0] += a.z*w.x; acc[2][1] += a.z*w.y; acc[2][2] += a.z*w.z; acc[2][3] += a.z*w.w;
      acc[3][0] += a.w*w.x; acc[3][1] += a.w*w.y; acc[3][2] += a.w*w.z; acc[3][3] += a.w*w.w;
    }
    __syncthreads();
  }
  #pragma unroll
  for (int i = 0; i < 4; i++){
    int r = row0 + r0 + i;
    if (r < M){
      float x0 = acc[i][0], x1 = acc[i][1], x2 = acc[i][2], x3 = acc[i][3];
      if (SCALE){
        float sc = scale[r];
        x0 *= sc; x1 *= sc; x2 *= sc; x3 *= sc;
      }
      if (RELU){ x0 = fmaxf(x0, 0.f); x1 = fmaxf(x1, 0.f); x2 = fmaxf(x2, 0.f); x3 = fmaxf(x3, 0.f); }
      uint2 o; o.x = fpack2(x0, x1); o.y = fpack2(x2, x3);
      *(uint2*)(outb + (size_t)r * 64 + tc * 2) = o;
    }
  }
}

// ---------- phase 1: h = relu(dinv[v]*(sum_in xws[s] + xws[v]) + b_gcn), xws = dinv*xw ----------
__global__ __launch_bounds__(256) void k_phase1(const u32* xws, const int* row_ptr, const int* col,
                                                const float* dinv, const float* b_gcn, u32* h_b, int n){
  int lane = threadIdx.x & 63;
  int v = blockIdx.x * 4 + (threadIdx.x >> 6);
  if (v >= n) return;
  u32 sp = xws[(size_t)v * 64 + lane];
  float ax = bf_lo(sp), ay = bf_hi(sp);
  int e0 = row_ptr[v], e1 = row_ptr[v + 1];
  for (int i = e0; i < e1; i += 4){
    int4 cs = *(const int4*)(col + i);
    u32 q0 = xws[(size_t)cs.x * 64 + lane];
    u32 q1 = xws[(size_t)cs.y * 64 + lane];
    u32 q2 = xws[(size_t)cs.z * 64 + lane];
    u32 q3 = xws[(size_t)cs.w * 64 + lane];
    ax += (bf_lo(q0) + bf_lo(q1)) + (bf_lo(q2) + bf_lo(q3));
    ay += (bf_hi(q0) + bf_hi(q1)) + (bf_hi(q2) + bf_hi(q3));
  }
  float dv = dinv[v];
  float2 bg = *(const float2*)(b_gcn + lane * 2);
  ax = fmaxf(fmaf(dv, ax, bg.x), 0.f);
  ay = fmaxf(fmaf(dv, ay, bg.y), 0.f);
  h_b[(size_t)v * 64 + lane] = fpack2(ax, ay);
}

// ---------- phase 2: aggx = sum h[src] + h[v]; agge = sum ea_csr (streaming) + ones ----------
__global__ __launch_bounds__(256) void k_phase2(const u32* h_b, const int* row_ptr, const int* col,
                                                const u32* ea_csr, const float* degf, u16* A2b, int n){
  int lane = threadIdx.x & 63;
  int v = blockIdx.x * 4 + (threadIdx.x >> 6);
  if (v >= n) return;
  u32 sp = h_b[(size_t)v * 64 + lane];
  float ax = bf_lo(sp), ay = bf_hi(sp);
  float ex = 0.f, ey = 0.f;
  int e0 = row_ptr[v], e1 = row_ptr[v + 1];
  for (int i = e0; i < e1; i += 4){
    int4 cs = *(const int4*)(col + i);
    u32 q0 = h_b[(size_t)cs.x * 64 + lane];
    u32 q1 = h_b[(size_t)cs.y * 64 + lane];
    u32 q2 = h_b[(size_t)cs.z * 64 + lane];
    u32 q3 = h_b[(size_t)cs.w * 64 + lane];
    if (lane < 32){
      u32 e = ea_csr[(size_t)i * 8 + lane];   // 4 edges x 8 u32, coalesced 128 B
      ex += bf_lo(e); ey += bf_hi(e);
    }
    ax += (bf_lo(q0) + bf_lo(q1)) + (bf_lo(q2) + bf_lo(q3));
    ay += (bf_hi(q0) + bf_hi(q1)) + (bf_hi(q2) + bf_hi(q3));
  }
  // reduce ea slots: lane l<32 holds edge-slot l>>3, ch-pair l&7
  ex += __shfl_xor(ex, 8);  ey += __shfl_xor(ey, 8);
  ex += __shfl_xor(ex, 16); ey += __shfl_xor(ey, 16);
  u16* rowp = A2b + (size_t)v * 160;
  ((u32*)rowp)[lane] = fpack2(ax, ay);
  if (lane < 8)       ((u32*)rowp)[64 + lane] = fpack2(ex + 1.0f, ey + 1.0f);
  else if (lane < 16) ((u32*)rowp)[64 + lane] = (lane == 8) ? (u32)f2bf(degf[v]) : 0u;
}

// ---------- pooling ----------
__global__ void k_starts(const int* batch, int* start, int n, int g){
  int v = blockIdx.x * blockDim.x + threadIdx.x;
  if (v >= n) return;
  int b = batch[v];
  int prev = (v == 0) ? -1 : batch[v - 1];
  for (int q = prev + 1; q <= b; ++q) start[q] = v;
  if (v == n - 1){ for (int q = b + 1; q <= g; ++q) start[q] = n; }
}
__global__ __launch_bounds__(256) void k_pool(const u32* h2_b, const int* start, float* pooled, int n){
  __shared__ float2 red[256];
  int g = blockIdx.x;
  int s0 = start[g], s1 = start[g + 1];
  int tid = threadIdx.x;
  int cu = tid & 63, rr = tid >> 6;
  float ax = 0.f, ay = 0.f;
  for (int r = s0 + rr; r < s1; r += 4){
    u32 q = h2_b[(size_t)r * 64 + cu];
    ax += bf_lo(q); ay += bf_hi(q);
  }
  red[tid] = make_float2(ax, ay);
  __syncthreads();
  if (rr == 0){
    #pragma unroll
    for (int p = 1; p < 4; p++){ float2 o = red[cu + (p << 6)]; ax += o.x; ay += o.y; }
    int c = s1 - s0; if (c < 1) c = 1;
    float inv = 1.0f / (float)c;
    pooled[g * DH + cu * 2]     = ax * inv;
    pooled[g * DH + cu * 2 + 1] = ay * inv;
  }
}
__global__ __launch_bounds__(128) void k_final(const float* pooled, const float* W_out,
                                               const float* b_out, float* out){
  __shared__ float pl[DH];
  int g = blockIdx.x, o = threadIdx.x;
  pl[o] = pooled[g * DH + o];
  __syncthreads();
  float acc = b_out[o];
  for (int k = 0; k < DH; ++k) acc += pl[k] * W_out[k * DO + o];
  out[g * DO + o] = acc;
}

extern "C" void kernel_launch(void* const* d_in, const int* in_sizes, int n_in,
                              void* d_out, int out_size, void* d_ws, size_t ws_size,
                              hipStream_t stream){
  const float* x         = (const float*)d_in[0];
  const int*   edge_index= (const int*)  d_in[1];
  const float* edge_attr = (const float*)d_in[2];
  const int*   batch     = (const int*)  d_in[3];
  const float* W_gcn     = (const float*)d_in[4];
  const float* b_gcn     = (const float*)d_in[5];
  const float* W_le      = (const float*)d_in[6];
  const float* b_le      = (const float*)d_in[7];
  const float* W_lin     = (const float*)d_in[8];
  const float* b_lin     = (const float*)d_in[9];
  const float* W_out     = (const float*)d_in[10];
  const float* b_out     = (const float*)d_in[11];
  float* out = (float*)d_out;

  const int n  = in_sizes[0] / DV;       // 100000
  const int e2 = in_sizes[1] / 2;        // 1600000 directed edges
  const int g  = out_size / DO;          // 64
  const int* srcp = edge_index;
  const int* dstp = edge_index + e2;
  const int e2pad = e2 + 3 * n + 4;      // CSR capacity with per-row pad-to-4

  char* ws = (char*)d_ws;
  size_t off = 0;
  auto alloc = [&](size_t bytes) -> char* {
    char* p = ws + off; off = (off + bytes + 255) & ~(size_t)255; return p;
  };

  int*   cnt     = (int*)  alloc((size_t)n * 4);
  int*   row_ptr = (int*)  alloc((size_t)(n + 1) * 4);
  int*   fill    = (int*)  alloc((size_t)n * 4);
  int*   partial = (int*)  alloc((size_t)n * 4);
  int*   bsums   = (int*)  alloc(512);
  int*   bexc    = (int*)  alloc(512);
  float* dinv    = (float*)alloc((size_t)n * 4);
  float* degf    = (float*)alloc((size_t)n * 4);
  int*   startg  = (int*)  alloc((size_t)(g + 1) * 4);
  float* pooled  = (float*)alloc((size_t)g * DH * 4);
  float* Wfull   = (float*)alloc(160 * DH * 4);
  u32*   h_b     = (u32*)  alloc((size_t)(n + 1) * 64 * 4);  // +1 zero row
  int*   col     = (int*)  alloc((size_t)e2pad * 4);
  // region A: xws (bf16, [N+1,128]) later overwritten by A2 (bf16, [N,160])
  size_t szXW = (size_t)(n + 1) * 64 * 4, szA2 = (size_t)n * 160 * 2;
  char* regionA = alloc(szA2 > szXW ? szA2 : szXW);
  u32* xws_b = (u32*)regionA;
  u16* A2b   = (u16*)regionA;
  // region B: ea_csr (bf16, [e2pad,16]) later overwritten by h2 (bf16, [N,128])
  size_t szEA = (size_t)e2pad * 32, szH2 = (size_t)n * 64 * 4;
  char* regionB = alloc(szEA > szH2 ? szEA : szH2);
  u32* ea_csr = (u32*)regionB;
  u32* h2_b   = (u32*)regionB;

  const int nb1024 = (n + 1023) / 1024;  // must be <= 128 for k_scan2

  k_init   <<<(n + 255) / 256, 256, 0, stream>>>(cnt, n);
  k_count  <<<(e2 + 255) / 256, 256, 0, stream>>>(dstp, cnt, e2);
  k_scan1  <<<nb1024, 256, 0, stream>>>(cnt, partial, bsums, n);
  k_scan2  <<<1, 128, 0, stream>>>(bsums, bexc, nb1024);
  k_scan3  <<<(n + 255) / 256, 256, 0, stream>>>(partial, bexc, row_ptr, n);
  k_prep   <<<(n + 255) / 256, 256, 0, stream>>>(row_ptr, cnt, fill, dinv, degf, n);
  k_scatter<<<(e2 + 255) / 256, 256, 0, stream>>>(srcp, dstp, fill, col, edge_attr, ea_csr, e2);
  k_pad    <<<(n + 255) / 256, 256, 0, stream>>>(row_ptr, cnt, col, ea_csr,
                                                 xws_b + (size_t)n * 64, h_b + (size_t)n * 64, n);
  k_wcombo <<<1, 128, 0, stream>>>(W_lin, b_lin, W_le, b_le, Wfull);

  k_gemm<DV, false, false, true><<<(n + 31) / 32, 256, 0, stream>>>(x, W_gcn, xws_b, dinv, n);
  k_phase1 <<<(n + 3) / 4, 256, 0, stream>>>(xws_b, row_ptr, col, dinv, b_gcn, h_b, n);
  k_phase2 <<<(n + 3) / 4, 256, 0, stream>>>(h_b, row_ptr, col, ea_csr, degf, A2b, n);
  k_gemm<160, true, true, false><<<(n + 31) / 32, 256, 0, stream>>>(A2b, Wfull, h2_b, (const float*)nullptr, n);

  k_starts <<<(n + 255) / 256, 256, 0, stream>>>(batch, startg, n, g);
  k_pool   <<<g, 256, 0, stream>>>(h2_b, startg, pooled, n);
  k_final  <<<g, 128, 0, stream>>>(pooled, W_out, b_out, out);
}

// Round 4
// 777.451 us; speedup vs baseline: 1.2790x; 1.0001x over previous
//
#include <hip/hip_runtime.h>
#include <hip/hip_bf16.h>
#include <cstddef>

typedef unsigned int  u32;
typedef unsigned short u16;

#define DV 128
#define DH 128
#define DE 16
#define DO 128

// ---------- bf16 helpers (bit tricks, RNE) ----------
__device__ inline float bf_lo(u32 u){ return __uint_as_float(u << 16); }
__device__ inline float bf_hi(u32 u){ return __uint_as_float(u & 0xFFFF0000u); }
__device__ inline u32 fpack2(float a, float b){
  u32 ua = __float_as_uint(a), ub = __float_as_uint(b);
  ua += 0x7FFFu + ((ua >> 16) & 1u);
  ub += 0x7FFFu + ((ub >> 16) & 1u);
  return (ua >> 16) | (ub & 0xFFFF0000u);
}
__device__ inline u16 f2bf(float a){
  u32 ua = __float_as_uint(a); ua += 0x7FFFu + ((ua >> 16) & 1u); return (u16)(ua >> 16);
}

// ---------- CSR build ----------
__global__ void k_init(int* cnt, int n){
  int v = blockIdx.x * blockDim.x + threadIdx.x;
  if (v < n) cnt[v] = 0;
}
__global__ void k_count(const int* dst, int* cnt, int e2){
  int j = blockIdx.x * blockDim.x + threadIdx.x;
  if (j < e2) atomicAdd(&cnt[dst[j]], 1);
}
// scan of PADDED counts: pc = (cnt+7)&~7  (rows padded to multiple of 8)
__global__ __launch_bounds__(256) void k_scan1(const int* cnt, int* partial, int* bsums, int n){
  __shared__ int lds[256];
  int t = threadIdx.x;
  int base = blockIdx.x * 1024 + t * 4;
  int v0=0,v1=0,v2=0,v3=0;
  if (base + 3 < n){ int4 q = *(const int4*)(cnt + base); v0=q.x; v1=q.y; v2=q.z; v3=q.w; }
  else {
    if (base + 0 < n) v0 = cnt[base];
    if (base + 1 < n) v1 = cnt[base+1];
    if (base + 2 < n) v2 = cnt[base+2];
  }
  v0 = (v0 + 7) & ~7; v1 = (v1 + 7) & ~7; v2 = (v2 + 7) & ~7; v3 = (v3 + 7) & ~7;
  v1 += v0; v2 += v1; v3 += v2;
  lds[t] = v3; __syncthreads();
  for (int off = 1; off < 256; off <<= 1){
    int x = (t >= off) ? lds[t - off] : 0;
    __syncthreads();
    lds[t] += x;
    __syncthreads();
  }
  int add = (t > 0) ? lds[t - 1] : 0;
  if (base + 3 < n){
    int4 q; q.x = v0+add; q.y = v1+add; q.z = v2+add; q.w = v3+add;
    *(int4*)(partial + base) = q;
  } else {
    if (base + 0 < n) partial[base]   = v0 + add;
    if (base + 1 < n) partial[base+1] = v1 + add;
    if (base + 2 < n) partial[base+2] = v2 + add;
  }
  if (t == 255) bsums[blockIdx.x] = lds[255];
}
__global__ void k_scan2(const int* bsums, int* bexc, int nb){
  __shared__ int lds[128];
  int t = threadIdx.x;
  lds[t] = (t < nb) ? bsums[t] : 0;
  __syncthreads();
  for (int off = 1; off < 128; off <<= 1){
    int x = (t >= off) ? lds[t - off] : 0;
    __syncthreads();
    lds[t] += x;
    __syncthreads();
  }
  if (t < nb) bexc[t] = (t > 0) ? lds[t - 1] : 0;
}
__global__ void k_scan3(const int* partial, const int* bexc, int* row_ptr, int n){
  int i = blockIdx.x * blockDim.x + threadIdx.x;
  if (i < n) row_ptr[i + 1] = partial[i] + bexc[i >> 10];
  if (i == 0) row_ptr[0] = 0;
}
__global__ void k_prep(const int* row_ptr, const int* cnt, int* fill, float* dinv, float* degf, int n){
  int v = blockIdx.x * blockDim.x + threadIdx.x;
  if (v < n){
    fill[v] = row_ptr[v];
    float c = (float)(cnt[v] + 1);   // in-degree + self-loop
    dinv[v] = rsqrtf(c);
    degf[v] = c;
  }
}
// scatter: one 8-B store per edge: {src node, edge id}
__global__ void k_scatter(const int* src, const int* dst, int* fill, int2* ce, int e2){
  int j = blockIdx.x * blockDim.x + threadIdx.x;
  if (j < e2){
    int d = dst[j];
    int pos = atomicAdd(&fill[d], 1);
    ce[pos] = make_int2(src[j], j);
  }
}
// fill CSR pad slots with {n, 0}; zero the gather tables' row n
__global__ void k_pad(const int* row_ptr, const int* cnt, int2* ce,
                      u32* xws_zrow, u32* h_zrow, int n){
  int v = blockIdx.x * blockDim.x + threadIdx.x;
  if (v < n){
    int s = row_ptr[v] + cnt[v], e = row_ptr[v + 1];
    for (int i = s; i < e; ++i) ce[i] = make_int2(n, 0);
  }
  if (blockIdx.x == 0 && threadIdx.x < 64){
    xws_zrow[threadIdx.x] = 0u;
    h_zrow[threadIdx.x] = 0u;
  }
}

// ---------- fold W_le@W_bot and biases into the h2 GEMM weight ----------
__global__ __launch_bounds__(128) void k_wcombo(const float* W_lin, const float* b_lin,
                                                const float* W_le, const float* b_le, float* Wfull){
  __shared__ float wle[DE * DH];
  int c = threadIdx.x;
  for (int i = c; i < DE * DH; i += 128) wle[i] = W_le[i];
  __syncthreads();
  float combo[DE];
  #pragma unroll
  for (int i = 0; i < DE; i++) combo[i] = 0.f;
  float bacc = b_lin[c];
  for (int k = 0; k < DH; ++k){
    float wv = W_lin[(size_t)(DH + k) * DH + c];   // W_bot[k][c]
    bacc += b_le[k] * wv;
    #pragma unroll
    for (int i = 0; i < DE; i++) combo[i] += wle[i * DH + k] * wv;
  }
  for (int r = 0; r < DH; ++r) Wfull[r * DH + c] = W_lin[r * DH + c];
  #pragma unroll
  for (int i = 0; i < DE; i++) Wfull[(DH + i) * DH + c] = combo[i];
  Wfull[144 * DH + c] = bacc;
  for (int r = 145; r < 160; ++r) Wfull[r * DH + c] = 0.f;
}

// ---------- register-tiled GEMM: [M,K] @ [K,128] -> bf16-packed out ----------
template<int K, bool RELU, bool ABF16, bool SCALE>
__global__ __launch_bounds__(256) void k_gemm(const void* Ap, const float* W, u32* outb,
                                              const float* scale, int M){
  __shared__ float Ws[32][128];
  __shared__ float At[32][36];
  int tid = threadIdx.x;
  int row0 = blockIdx.x * 32;
  int tc = tid & 31, tr = tid >> 5;
  int c0 = tc * 4, r0 = tr * 4;
  float acc[4][4];
  #pragma unroll
  for (int i = 0; i < 4; i++)
    #pragma unroll
    for (int j = 0; j < 4; j++) acc[i][j] = 0.f;
  int lr = tid >> 3;
  int lk = (tid & 7) * 4;
  for (int kc = 0; kc < K; kc += 32){
    int gr = row0 + lr; if (gr > M - 1) gr = M - 1;
    if (ABF16){
      const u16* A = (const u16*)Ap;
      uint2 q = *(const uint2*)(A + (size_t)gr * K + kc + lk);
      At[lk+0][lr] = bf_lo(q.x); At[lk+1][lr] = bf_hi(q.x);
      At[lk+2][lr] = bf_lo(q.y); At[lk+3][lr] = bf_hi(q.y);
    } else {
      const float* A = (const float*)Ap;
      float4 q = *(const float4*)(A + (size_t)gr * K + kc + lk);
      At[lk+0][lr] = q.x; At[lk+1][lr] = q.y; At[lk+2][lr] = q.z; At[lk+3][lr] = q.w;
    }
    {
      int c4 = (tid & 31) * 4, kb = tid >> 5;
      #pragma unroll
      for (int p = 0; p < 4; p++){
        int kr = kb + p * 8;
        *(float4*)&Ws[kr][c4] = *(const float4*)(W + (size_t)(kc + kr) * DH + c4);
      }
    }
    __syncthreads();
    #pragma unroll
    for (int kk = 0; kk < 32; ++kk){
      float4 w = *(const float4*)&Ws[kk][c0];
      float4 a = *(const float4*)&At[kk][r0];
      acc[0][0] += a.x*w.x; acc[0][1] += a.x*w.y; acc[0][2] += a.x*w.z; acc[0][3] += a.x*w.w;
      acc[1][0] += a.y*w.x; acc[1][1] += a.y*w.y; acc[1][2] += a.y*w.z; acc[1][3] += a.y*w.w;
      acc[2][0] += a.z*w.x; acc[2][1] += a.z*w.y; acc[2][2] += a.z*w.z; acc[2][3] += a.z*w.w;
      acc[3][0] += a.w*w.x; acc[3][1] += a.w*w.y; acc[3][2] += a.w*w.z; acc[3][3] += a.w*w.w;
    }
    __syncthreads();
  }
  #pragma unroll
  for (int i = 0; i < 4; i++){
    int r = row0 + r0 + i;
    if (r < M){
      float x0 = acc[i][0], x1 = acc[i][1], x2 = acc[i][2], x3 = acc[i][3];
      if (SCALE){
        float sc = scale[r];
        x0 *= sc; x1 *= sc; x2 *= sc; x3 *= sc;
      }
      if (RELU){ x0 = fmaxf(x0, 0.f); x1 = fmaxf(x1, 0.f); x2 = fmaxf(x2, 0.f); x3 = fmaxf(x3, 0.f); }
      uint2 o; o.x = fpack2(x0, x1); o.y = fpack2(x2, x3);
      *(uint2*)(outb + (size_t)r * 64 + tc * 2) = o;
    }
  }
}

// ---------- phase 1: h = relu(dinv[v]*(sum_in xws[s] + xws[v]) + b_gcn), xws = dinv*xw ----------
// rows padded to 8 -> 8 gathers in flight per wave
__global__ __launch_bounds__(256) void k_phase1(const u32* xws, const int* row_ptr, const int2* ce,
                                                const float* dinv, const float* b_gcn, u32* h_b, int n){
  int lane = threadIdx.x & 63;
  int v = blockIdx.x * 4 + (threadIdx.x >> 6);
  if (v >= n) return;
  u32 sp = xws[(size_t)v * 64 + lane];
  float ax = bf_lo(sp), ay = bf_hi(sp);
  int e0 = row_ptr[v], e1 = row_ptr[v + 1];
  for (int i = e0; i < e1; i += 8){
    const int4* cp = (const int4*)(ce + i);
    int4 A = cp[0], B = cp[1], C = cp[2], D = cp[3];
    u32 q0 = xws[(size_t)A.x * 64 + lane];
    u32 q1 = xws[(size_t)A.z * 64 + lane];
    u32 q2 = xws[(size_t)B.x * 64 + lane];
    u32 q3 = xws[(size_t)B.z * 64 + lane];
    u32 q4 = xws[(size_t)C.x * 64 + lane];
    u32 q5 = xws[(size_t)C.z * 64 + lane];
    u32 q6 = xws[(size_t)D.x * 64 + lane];
    u32 q7 = xws[(size_t)D.z * 64 + lane];
    ax += ((bf_lo(q0) + bf_lo(q1)) + (bf_lo(q2) + bf_lo(q3)))
        + ((bf_lo(q4) + bf_lo(q5)) + (bf_lo(q6) + bf_lo(q7)));
    ay += ((bf_hi(q0) + bf_hi(q1)) + (bf_hi(q2) + bf_hi(q3)))
        + ((bf_hi(q4) + bf_hi(q5)) + (bf_hi(q6) + bf_hi(q7)));
  }
  float dv = dinv[v];
  float2 bg = *(const float2*)(b_gcn + lane * 2);
  ax = fmaxf(fmaf(dv, ax, bg.x), 0.f);
  ay = fmaxf(fmaf(dv, ay, bg.y), 0.f);
  h_b[(size_t)v * 64 + lane] = fpack2(ax, ay);
}

// ---------- phase 2: aggx = sum h[src] + h[v]; agge = gather edge_attr rows + ones ----------
__global__ __launch_bounds__(256) void k_phase2(const u32* h_b, const int* row_ptr, const int2* ce,
                                                const float* edge_attr, const float* degf,
                                                u16* A2b, int n){
  int lane = threadIdx.x & 63;
  int v = blockIdx.x * 4 + (threadIdx.x >> 6);
  if (v >= n) return;
  u32 sp = h_b[(size_t)v * 64 + lane];
  float ax = bf_lo(sp), ay = bf_hi(sp);
  float es = 0.f;                 // per-lane: channel lane&15, slot-group lane>>4
  int ch = lane & 15, grp = lane >> 4;
  int e0 = row_ptr[v], e1 = row_ptr[v + 1];
  for (int i = e0; i < e1; i += 8){
    const int4* cp = (const int4*)(ce + i);
    int4 A = cp[0], B = cp[1], C = cp[2], D = cp[3];
    // per-lane slot data for ea gather (broadcast 8-B loads, L1-resident)
    int2 c0 = ce[i + grp];
    int2 c1 = ce[i + 4 + grp];
    u32 q0 = h_b[(size_t)A.x * 64 + lane];
    u32 q1 = h_b[(size_t)A.z * 64 + lane];
    u32 q2 = h_b[(size_t)B.x * 64 + lane];
    u32 q3 = h_b[(size_t)B.z * 64 + lane];
    u32 q4 = h_b[(size_t)C.x * 64 + lane];
    u32 q5 = h_b[(size_t)C.z * 64 + lane];
    u32 q6 = h_b[(size_t)D.x * 64 + lane];
    u32 q7 = h_b[(size_t)D.z * 64 + lane];
    float m0 = (c0.x != n) ? 1.f : 0.f;
    float m1 = (c1.x != n) ? 1.f : 0.f;
    float v0 = edge_attr[(size_t)(c0.y >> 1) * DE + ch];
    float v1 = edge_attr[(size_t)(c1.y >> 1) * DE + ch];
    es = fmaf(m0, v0, es);
    es = fmaf(m1, v1, es);
    ax += ((bf_lo(q0) + bf_lo(q1)) + (bf_lo(q2) + bf_lo(q3)))
        + ((bf_lo(q4) + bf_lo(q5)) + (bf_lo(q6) + bf_lo(q7)));
    ay += ((bf_hi(q0) + bf_hi(q1)) + (bf_hi(q2) + bf_hi(q3)))
        + ((bf_hi(q4) + bf_hi(q5)) + (bf_hi(q6) + bf_hi(q7)));
  }
  // reduce slot groups: all lanes end with per-channel total
  es += __shfl_xor(es, 16);
  es += __shfl_xor(es, 32);
  // WAVE-UNIFORM shuffles (ds_bpermute sources must be active lanes —
  // doing this inside `if(lane<8)` reads from masked-off lanes = garbage)
  float c0v = __shfl(es, (lane & 7) * 2);
  float c1v = __shfl(es, (lane & 7) * 2 + 1);
  u16* rowp = A2b + (size_t)v * 160;
  ((u32*)rowp)[lane] = fpack2(ax, ay);
  if (lane < 8){
    ((u32*)rowp)[64 + lane] = fpack2(c0v + 1.0f, c1v + 1.0f);
  } else if (lane < 16){
    ((u32*)rowp)[64 + lane] = (lane == 8) ? (u32)f2bf(degf[v]) : 0u;
  }
}

// ---------- pooling ----------
__global__ void k_starts(const int* batch, int* start, int n, int g){
  int v = blockIdx.x * blockDim.x + threadIdx.x;
  if (v >= n) return;
  int b = batch[v];
  int prev = (v == 0) ? -1 : batch[v - 1];
  for (int q = prev + 1; q <= b; ++q) start[q] = v;
  if (v == n - 1){ for (int q = b + 1; q <= g; ++q) start[q] = n; }
}
__global__ __launch_bounds__(256) void k_pool(const u32* h2_b, const int* start, float* pooled, int n){
  __shared__ float2 red[256];
  int g = blockIdx.x;
  int s0 = start[g], s1 = start[g + 1];
  int tid = threadIdx.x;
  int cu = tid & 63, rr = tid >> 6;
  float ax = 0.f, ay = 0.f;
  for (int r = s0 + rr; r < s1; r += 4){
    u32 q = h2_b[(size_t)r * 64 + cu];
    ax += bf_lo(q); ay += bf_hi(q);
  }
  red[tid] = make_float2(ax, ay);
  __syncthreads();
  if (rr == 0){
    #pragma unroll
    for (int p = 1; p < 4; p++){ float2 o = red[cu + (p << 6)]; ax += o.x; ay += o.y; }
    int c = s1 - s0; if (c < 1) c = 1;
    float inv = 1.0f / (float)c;
    pooled[g * DH + cu * 2]     = ax * inv;
    pooled[g * DH + cu * 2 + 1] = ay * inv;
  }
}
__global__ __launch_bounds__(128) void k_final(const float* pooled, const float* W_out,
                                               const float* b_out, float* out){
  __shared__ float pl[DH];
  int g = blockIdx.x, o = threadIdx.x;
  pl[o] = pooled[g * DH + o];
  __syncthreads();
  float acc = b_out[o];
  for (int k = 0; k < DH; ++k) acc += pl[k] * W_out[k * DO + o];
  out[g * DO + o] = acc;
}

extern "C" void kernel_launch(void* const* d_in, const int* in_sizes, int n_in,
                              void* d_out, int out_size, void* d_ws, size_t ws_size,
                              hipStream_t stream){
  const float* x         = (const float*)d_in[0];
  const int*   edge_index= (const int*)  d_in[1];
  const float* edge_attr = (const float*)d_in[2];
  const int*   batch     = (const int*)  d_in[3];
  const float* W_gcn     = (const float*)d_in[4];
  const float* b_gcn     = (const float*)d_in[5];
  const float* W_le      = (const float*)d_in[6];
  const float* b_le      = (const float*)d_in[7];
  const float* W_lin     = (const float*)d_in[8];
  const float* b_lin     = (const float*)d_in[9];
  const float* W_out     = (const float*)d_in[10];
  const float* b_out     = (const float*)d_in[11];
  float* out = (float*)d_out;

  const int n  = in_sizes[0] / DV;       // 100000
  const int e2 = in_sizes[1] / 2;        // 1600000 directed edges
  const int g  = out_size / DO;          // 64
  const int* srcp = edge_index;
  const int* dstp = edge_index + e2;
  const int e2pad = e2 + 7 * n + 8;      // CSR capacity with per-row pad-to-8

  char* ws = (char*)d_ws;
  size_t off = 0;
  auto alloc = [&](size_t bytes) -> char* {
    char* p = ws + off; off = (off + bytes + 255) & ~(size_t)255; return p;
  };

  int*   cnt     = (int*)  alloc((size_t)n * 4);
  int*   row_ptr = (int*)  alloc((size_t)(n + 1) * 4);
  int*   fill    = (int*)  alloc((size_t)n * 4);
  int*   partial = (int*)  alloc((size_t)n * 4);
  int*   bsums   = (int*)  alloc(512);
  int*   bexc    = (int*)  alloc(512);
  float* dinv    = (float*)alloc((size_t)n * 4);
  float* degf    = (float*)alloc((size_t)n * 4);
  int*   startg  = (int*)  alloc((size_t)(g + 1) * 4);
  float* pooled  = (float*)alloc((size_t)g * DH * 4);
  float* Wfull   = (float*)alloc(160 * DH * 4);
  u32*   h_b     = (u32*)  alloc((size_t)(n + 1) * 64 * 4);  // +1 zero row
  int2*  ce      = (int2*) alloc((size_t)e2pad * 8);
  u32*   h2_b    = (u32*)  alloc((size_t)n * 64 * 4);
  // region A: xws (bf16, [N+1,128]) later overwritten by A2 (bf16, [N,160])
  size_t szXW = (size_t)(n + 1) * 64 * 4, szA2 = (size_t)n * 160 * 2;
  char* regionA = alloc(szA2 > szXW ? szA2 : szXW);
  u32* xws_b = (u32*)regionA;
  u16* A2b   = (u16*)regionA;

  const int nb1024 = (n + 1023) / 1024;  // must be <= 128 for k_scan2

  k_init   <<<(n + 255) / 256, 256, 0, stream>>>(cnt, n);
  k_count  <<<(e2 + 255) / 256, 256, 0, stream>>>(dstp, cnt, e2);
  k_scan1  <<<nb1024, 256, 0, stream>>>(cnt, partial, bsums, n);
  k_scan2  <<<1, 128, 0, stream>>>(bsums, bexc, nb1024);
  k_scan3  <<<(n + 255) / 256, 256, 0, stream>>>(partial, bexc, row_ptr, n);
  k_prep   <<<(n + 255) / 256, 256, 0, stream>>>(row_ptr, cnt, fill, dinv, degf, n);
  k_scatter<<<(e2 + 255) / 256, 256, 0, stream>>>(srcp, dstp, fill, ce, e2);
  k_pad    <<<(n + 255) / 256, 256, 0, stream>>>(row_ptr, cnt, ce,
                                                 xws_b + (size_t)n * 64, h_b + (size_t)n * 64, n);
  k_wcombo <<<1, 128, 0, stream>>>(W_lin, b_lin, W_le, b_le, Wfull);

  k_gemm<DV, false, false, true><<<(n + 31) / 32, 256, 0, stream>>>(x, W_gcn, xws_b, dinv, n);
  k_phase1 <<<(n + 3) / 4, 256, 0, stream>>>(xws_b, row_ptr, ce, dinv, b_gcn, h_b, n);
  k_phase2 <<<(n + 3) / 4, 256, 0, stream>>>(h_b, row_ptr, ce, edge_attr, degf, A2b, n);
  k_gemm<160, true, true, false><<<(n + 31) / 32, 256, 0, stream>>>(A2b, Wfull, h2_b, (const float*)nullptr, n);

  k_starts <<<(n + 255) / 256, 256, 0, stream>>>(batch, startg, n, g);
  k_pool   <<<g, 256, 0, stream>>>(h2_b, startg, pooled, n);
  k_final  <<<g, 128, 0, stream>>>(pooled, W_out, b_out, out);
}

// Round 5
// 682.650 us; speedup vs baseline: 1.4567x; 1.1389x over previous
//
#include <hip/hip_runtime.h>
#include <hip/hip_bf16.h>
#include <cstddef>

typedef unsigned int  u32;
typedef unsigned short u16;

#define DV 128
#define DH 128
#define DE 16
#define DO 128

// ---------- bf16 helpers (bit tricks, RNE) ----------
__device__ inline float bf_lo(u32 u){ return __uint_as_float(u << 16); }
__device__ inline float bf_hi(u32 u){ return __uint_as_float(u & 0xFFFF0000u); }
__device__ inline u32 fpack2(float a, float b){
  u32 ua = __float_as_uint(a), ub = __float_as_uint(b);
  ua += 0x7FFFu + ((ua >> 16) & 1u);
  ub += 0x7FFFu + ((ub >> 16) & 1u);
  return (ua >> 16) | (ub & 0xFFFF0000u);
}
__device__ inline u16 f2bf(float a){
  u32 ua = __float_as_uint(a); ua += 0x7FFFu + ((ua >> 16) & 1u); return (u16)(ua >> 16);
}

// ---------- CSR build ----------
__global__ void k_init(int* cnt, int n){
  int v = blockIdx.x * blockDim.x + threadIdx.x;
  if (v < n) cnt[v] = 0;
}
// count AND record each edge's rank within its dst bucket (coalesced store)
__global__ void k_count(const int* dst, int* cnt, int* rank, int e2){
  int j = blockIdx.x * blockDim.x + threadIdx.x;
  if (j < e2) rank[j] = atomicAdd(&cnt[dst[j]], 1);
}
// scan of PADDED counts: pc = (cnt+7)&~7  (rows padded to multiple of 8)
__global__ __launch_bounds__(256) void k_scan1(const int* cnt, int* partial, int* bsums, int n){
  __shared__ int lds[256];
  int t = threadIdx.x;
  int base = blockIdx.x * 1024 + t * 4;
  int v0=0,v1=0,v2=0,v3=0;
  if (base + 3 < n){ int4 q = *(const int4*)(cnt + base); v0=q.x; v1=q.y; v2=q.z; v3=q.w; }
  else {
    if (base + 0 < n) v0 = cnt[base];
    if (base + 1 < n) v1 = cnt[base+1];
    if (base + 2 < n) v2 = cnt[base+2];
  }
  v0 = (v0 + 7) & ~7; v1 = (v1 + 7) & ~7; v2 = (v2 + 7) & ~7; v3 = (v3 + 7) & ~7;
  v1 += v0; v2 += v1; v3 += v2;
  lds[t] = v3; __syncthreads();
  for (int off = 1; off < 256; off <<= 1){
    int x = (t >= off) ? lds[t - off] : 0;
    __syncthreads();
    lds[t] += x;
    __syncthreads();
  }
  int add = (t > 0) ? lds[t - 1] : 0;
  if (base + 3 < n){
    int4 q; q.x = v0+add; q.y = v1+add; q.z = v2+add; q.w = v3+add;
    *(int4*)(partial + base) = q;
  } else {
    if (base + 0 < n) partial[base]   = v0 + add;
    if (base + 1 < n) partial[base+1] = v1 + add;
    if (base + 2 < n) partial[base+2] = v2 + add;
  }
  if (t == 255) bsums[blockIdx.x] = lds[255];
}
__global__ void k_scan2(const int* bsums, int* bexc, int nb){
  __shared__ int lds[128];
  int t = threadIdx.x;
  lds[t] = (t < nb) ? bsums[t] : 0;
  __syncthreads();
  for (int off = 1; off < 128; off <<= 1){
    int x = (t >= off) ? lds[t - off] : 0;
    __syncthreads();
    lds[t] += x;
    __syncthreads();
  }
  if (t < nb) bexc[t] = (t > 0) ? lds[t - 1] : 0;
}
__global__ void k_scan3(const int* partial, const int* bexc, int* row_ptr, int n){
  int i = blockIdx.x * blockDim.x + threadIdx.x;
  if (i < n) row_ptr[i + 1] = partial[i] + bexc[i >> 10];
  if (i == 0) row_ptr[0] = 0;
}
__global__ void k_prep(const int* cnt, float* dinv, float* degf, int n){
  int v = blockIdx.x * blockDim.x + threadIdx.x;
  if (v < n){
    float c = (float)(cnt[v] + 1);   // in-degree + self-loop
    dinv[v] = rsqrtf(c);
    degf[v] = c;
  }
}
// scatter WITHOUT atomic: pos = row_ptr[dst] + precomputed rank
__global__ void k_scatter(const int* src, const int* dst, const int* rank,
                          const int* row_ptr, int2* ce, int e2){
  int j = blockIdx.x * blockDim.x + threadIdx.x;
  if (j < e2){
    int d = dst[j];
    int pos = row_ptr[d] + rank[j];
    ce[pos] = make_int2(src[j], j);
  }
}
// fill CSR pad slots with {n, 0}; zero the gather tables' row n
__global__ void k_pad(const int* row_ptr, const int* cnt, int2* ce,
                      u32* xws_zrow, u32* h_zrow, int n){
  int v = blockIdx.x * blockDim.x + threadIdx.x;
  if (v < n){
    int s = row_ptr[v] + cnt[v], e = row_ptr[v + 1];
    for (int i = s; i < e; ++i) ce[i] = make_int2(n, 0);
  }
  if (blockIdx.x == 0 && threadIdx.x < 64){
    xws_zrow[threadIdx.x] = 0u;
    h_zrow[threadIdx.x] = 0u;
  }
}

// ---------- fold W_le@W_bot and biases into the h2 GEMM weight ----------
__global__ __launch_bounds__(128) void k_wcombo(const float* W_lin, const float* b_lin,
                                                const float* W_le, const float* b_le, float* Wfull){
  __shared__ float wle[DE * DH];
  int c = threadIdx.x;
  for (int i = c; i < DE * DH; i += 128) wle[i] = W_le[i];
  __syncthreads();
  float combo[DE];
  #pragma unroll
  for (int i = 0; i < DE; i++) combo[i] = 0.f;
  float bacc = b_lin[c];
  for (int k = 0; k < DH; ++k){
    float wv = W_lin[(size_t)(DH + k) * DH + c];   // W_bot[k][c]
    bacc += b_le[k] * wv;
    #pragma unroll
    for (int i = 0; i < DE; i++) combo[i] += wle[i * DH + k] * wv;
  }
  for (int r = 0; r < DH; ++r) Wfull[r * DH + c] = W_lin[r * DH + c];
  #pragma unroll
  for (int i = 0; i < DE; i++) Wfull[(DH + i) * DH + c] = combo[i];
  Wfull[144 * DH + c] = bacc;
  for (int r = 145; r < 160; ++r) Wfull[r * DH + c] = 0.f;
}

// ---------- register-tiled GEMM: [M,K] @ [K,128] -> bf16-packed out ----------
template<int K, bool RELU, bool ABF16, bool SCALE>
__global__ __launch_bounds__(256) void k_gemm(const void* Ap, const float* W, u32* outb,
                                              const float* scale, int M){
  __shared__ float Ws[32][128];
  __shared__ float At[32][36];
  int tid = threadIdx.x;
  int row0 = blockIdx.x * 32;
  int tc = tid & 31, tr = tid >> 5;
  int c0 = tc * 4, r0 = tr * 4;
  float acc[4][4];
  #pragma unroll
  for (int i = 0; i < 4; i++)
    #pragma unroll
    for (int j = 0; j < 4; j++) acc[i][j] = 0.f;
  int lr = tid >> 3;
  int lk = (tid & 7) * 4;
  for (int kc = 0; kc < K; kc += 32){
    int gr = row0 + lr; if (gr > M - 1) gr = M - 1;
    if (ABF16){
      const u16* A = (const u16*)Ap;
      uint2 q = *(const uint2*)(A + (size_t)gr * K + kc + lk);
      At[lk+0][lr] = bf_lo(q.x); At[lk+1][lr] = bf_hi(q.x);
      At[lk+2][lr] = bf_lo(q.y); At[lk+3][lr] = bf_hi(q.y);
    } else {
      const float* A = (const float*)Ap;
      float4 q = *(const float4*)(A + (size_t)gr * K + kc + lk);
      At[lk+0][lr] = q.x; At[lk+1][lr] = q.y; At[lk+2][lr] = q.z; At[lk+3][lr] = q.w;
    }
    {
      int c4 = (tid & 31) * 4, kb = tid >> 5;
      #pragma unroll
      for (int p = 0; p < 4; p++){
        int kr = kb + p * 8;
        *(float4*)&Ws[kr][c4] = *(const float4*)(W + (size_t)(kc + kr) * DH + c4);
      }
    }
    __syncthreads();
    #pragma unroll
    for (int kk = 0; kk < 32; ++kk){
      float4 w = *(const float4*)&Ws[kk][c0];
      float4 a = *(const float4*)&At[kk][r0];
      acc[0][0] += a.x*w.x; acc[0][1] += a.x*w.y; acc[0][2] += a.x*w.z; acc[0][3] += a.x*w.w;
      acc[1][0] += a.y*w.x; acc[1][1] += a.y*w.y; acc[1][2] += a.y*w.z; acc[1][3] += a.y*w.w;
      acc[2][0] += a.z*w.x; acc[2][1] += a.z*w.y; acc[2][2] += a.z*w.z; acc[2][3] += a.z*w.w;
      acc[3][0] += a.w*w.x; acc[3][1] += a.w*w.y; acc[3][2] += a.w*w.z; acc[3][3] += a.w*w.w;
    }
    __syncthreads();
  }
  #pragma unroll
  for (int i = 0; i < 4; i++){
    int r = row0 + r0 + i;
    if (r < M){
      float x0 = acc[i][0], x1 = acc[i][1], x2 = acc[i][2], x3 = acc[i][3];
      if (SCALE){
        float sc = scale[r];
        x0 *= sc; x1 *= sc; x2 *= sc; x3 *= sc;
      }
      if (RELU){ x0 = fmaxf(x0, 0.f); x1 = fmaxf(x1, 0.f); x2 = fmaxf(x2, 0.f); x3 = fmaxf(x3, 0.f); }
      uint2 o; o.x = fpack2(x0, x1); o.y = fpack2(x2, x3);
      *(uint2*)(outb + (size_t)r * 64 + tc * 2) = o;
    }
  }
}

// ---------- phase 1: 2 nodes per wave (32 lanes x uint2 each), 16 gathers in flight ----------
__global__ __launch_bounds__(256) void k_phase1(const u32* xws, const int* row_ptr, const int2* ce,
                                                const float* dinv, const float* b_gcn, u32* h_b, int n){
  int lane = threadIdx.x & 63;
  int ln = lane & 31;
  int v = blockIdx.x * 8 + ((threadIdx.x >> 6) << 1) + (lane >> 5);
  if (v >= n) return;
  uint2 sp = *(const uint2*)(xws + (size_t)v * 64 + ln * 2);
  float a0 = bf_lo(sp.x), a1 = bf_hi(sp.x), a2 = bf_lo(sp.y), a3 = bf_hi(sp.y);
  int e0 = row_ptr[v], e1 = row_ptr[v + 1];
  for (int i = e0; i < e1; i += 8){
    const int4* cp = (const int4*)(ce + i);
    int4 A = cp[0], B = cp[1], C = cp[2], D = cp[3];
    uint2 q0 = *(const uint2*)(xws + (size_t)A.x * 64 + ln * 2);
    uint2 q1 = *(const uint2*)(xws + (size_t)A.z * 64 + ln * 2);
    uint2 q2 = *(const uint2*)(xws + (size_t)B.x * 64 + ln * 2);
    uint2 q3 = *(const uint2*)(xws + (size_t)B.z * 64 + ln * 2);
    uint2 q4 = *(const uint2*)(xws + (size_t)C.x * 64 + ln * 2);
    uint2 q5 = *(const uint2*)(xws + (size_t)C.z * 64 + ln * 2);
    uint2 q6 = *(const uint2*)(xws + (size_t)D.x * 64 + ln * 2);
    uint2 q7 = *(const uint2*)(xws + (size_t)D.z * 64 + ln * 2);
    a0 += ((bf_lo(q0.x) + bf_lo(q1.x)) + (bf_lo(q2.x) + bf_lo(q3.x)))
        + ((bf_lo(q4.x) + bf_lo(q5.x)) + (bf_lo(q6.x) + bf_lo(q7.x)));
    a1 += ((bf_hi(q0.x) + bf_hi(q1.x)) + (bf_hi(q2.x) + bf_hi(q3.x)))
        + ((bf_hi(q4.x) + bf_hi(q5.x)) + (bf_hi(q6.x) + bf_hi(q7.x)));
    a2 += ((bf_lo(q0.y) + bf_lo(q1.y)) + (bf_lo(q2.y) + bf_lo(q3.y)))
        + ((bf_lo(q4.y) + bf_lo(q5.y)) + (bf_lo(q6.y) + bf_lo(q7.y)));
    a3 += ((bf_hi(q0.y) + bf_hi(q1.y)) + (bf_hi(q2.y) + bf_hi(q3.y)))
        + ((bf_hi(q4.y) + bf_hi(q5.y)) + (bf_hi(q6.y) + bf_hi(q7.y)));
  }
  float dv = dinv[v];
  float4 bg = *(const float4*)(b_gcn + ln * 4);
  a0 = fmaxf(fmaf(dv, a0, bg.x), 0.f);
  a1 = fmaxf(fmaf(dv, a1, bg.y), 0.f);
  a2 = fmaxf(fmaf(dv, a2, bg.z), 0.f);
  a3 = fmaxf(fmaf(dv, a3, bg.w), 0.f);
  uint2 o; o.x = fpack2(a0, a1); o.y = fpack2(a2, a3);
  *(uint2*)(h_b + (size_t)v * 64 + ln * 2) = o;
}

// ---------- phase 2: 2 nodes per wave; aggx gather + streaming-ish ea gather ----------
__global__ __launch_bounds__(256) void k_phase2(const u32* h_b, const int* row_ptr, const int2* ce,
                                                const float* edge_attr, const float* degf,
                                                u16* A2b, int n){
  int lane = threadIdx.x & 63;
  int ln = lane & 31;
  int half = lane >> 5;
  int v = blockIdx.x * 8 + ((threadIdx.x >> 6) << 1) + half;
  if (v >= n) return;
  uint2 sp = *(const uint2*)(h_b + (size_t)v * 64 + ln * 2);
  float a0 = bf_lo(sp.x), a1 = bf_hi(sp.x), a2 = bf_lo(sp.y), a3 = bf_hi(sp.y);
  float es = 0.f;                  // channel ln&15, slot-group ln>>4 (4 edges each)
  int ch = ln & 15, grp = ln >> 4;
  int e0 = row_ptr[v], e1 = row_ptr[v + 1];
  for (int i = e0; i < e1; i += 8){
    const int4* cp = (const int4*)(ce + i);
    int4 A = cp[0], B = cp[1], C = cp[2], D = cp[3];
    int gb = i + grp * 4;
    int2 c0 = ce[gb + 0];
    int2 c1 = ce[gb + 1];
    int2 c2 = ce[gb + 2];
    int2 c3 = ce[gb + 3];
    uint2 q0 = *(const uint2*)(h_b + (size_t)A.x * 64 + ln * 2);
    uint2 q1 = *(const uint2*)(h_b + (size_t)A.z * 64 + ln * 2);
    uint2 q2 = *(const uint2*)(h_b + (size_t)B.x * 64 + ln * 2);
    uint2 q3 = *(const uint2*)(h_b + (size_t)B.z * 64 + ln * 2);
    uint2 q4 = *(const uint2*)(h_b + (size_t)C.x * 64 + ln * 2);
    uint2 q5 = *(const uint2*)(h_b + (size_t)C.z * 64 + ln * 2);
    uint2 q6 = *(const uint2*)(h_b + (size_t)D.x * 64 + ln * 2);
    uint2 q7 = *(const uint2*)(h_b + (size_t)D.z * 64 + ln * 2);
    float m0 = (c0.x != n) ? 1.f : 0.f;
    float m1 = (c1.x != n) ? 1.f : 0.f;
    float m2 = (c2.x != n) ? 1.f : 0.f;
    float m3 = (c3.x != n) ? 1.f : 0.f;
    float v0 = edge_attr[(size_t)(c0.y >> 1) * DE + ch];
    float v1 = edge_attr[(size_t)(c1.y >> 1) * DE + ch];
    float v2 = edge_attr[(size_t)(c2.y >> 1) * DE + ch];
    float v3 = edge_attr[(size_t)(c3.y >> 1) * DE + ch];
    es = fmaf(m0, v0, es);
    es = fmaf(m1, v1, es);
    es = fmaf(m2, v2, es);
    es = fmaf(m3, v3, es);
    a0 += ((bf_lo(q0.x) + bf_lo(q1.x)) + (bf_lo(q2.x) + bf_lo(q3.x)))
        + ((bf_lo(q4.x) + bf_lo(q5.x)) + (bf_lo(q6.x) + bf_lo(q7.x)));
    a1 += ((bf_hi(q0.x) + bf_hi(q1.x)) + (bf_hi(q2.x) + bf_hi(q3.x)))
        + ((bf_hi(q4.x) + bf_hi(q5.x)) + (bf_hi(q6.x) + bf_hi(q7.x)));
    a2 += ((bf_lo(q0.y) + bf_lo(q1.y)) + (bf_lo(q2.y) + bf_lo(q3.y)))
        + ((bf_lo(q4.y) + bf_lo(q5.y)) + (bf_lo(q6.y) + bf_lo(q7.y)));
    a3 += ((bf_hi(q0.y) + bf_hi(q1.y)) + (bf_hi(q2.y) + bf_hi(q3.y)))
        + ((bf_hi(q4.y) + bf_hi(q5.y)) + (bf_hi(q6.y) + bf_hi(q7.y)));
  }
  // within-half reduction over the 2 slot groups, then wave-uniform pair pick
  es += __shfl_xor(es, 16);
  float c0v = __shfl(es, half * 32 + (ln & 7) * 2);
  float c1v = __shfl(es, half * 32 + (ln & 7) * 2 + 1);
  u32* rowp = (u32*)(A2b + (size_t)v * 160);
  uint2 o; o.x = fpack2(a0, a1); o.y = fpack2(a2, a3);
  *(uint2*)(rowp + ln * 2) = o;
  if (ln < 8){
    rowp[64 + ln] = fpack2(c0v + 1.0f, c1v + 1.0f);
  } else if (ln < 16){
    rowp[64 + ln] = (ln == 8) ? (u32)f2bf(degf[v]) : 0u;
  }
}

// ---------- pooling ----------
__global__ void k_starts(const int* batch, int* start, int n, int g){
  int v = blockIdx.x * blockDim.x + threadIdx.x;
  if (v >= n) return;
  int b = batch[v];
  int prev = (v == 0) ? -1 : batch[v - 1];
  for (int q = prev + 1; q <= b; ++q) start[q] = v;
  if (v == n - 1){ for (int q = b + 1; q <= g; ++q) start[q] = n; }
}
__global__ __launch_bounds__(256) void k_pool(const u32* h2_b, const int* start, float* pooled, int n){
  __shared__ float2 red[256];
  int g = blockIdx.x;
  int s0 = start[g], s1 = start[g + 1];
  int tid = threadIdx.x;
  int cu = tid & 63, rr = tid >> 6;
  float ax = 0.f, ay = 0.f;
  for (int r = s0 + rr; r < s1; r += 4){
    u32 q = h2_b[(size_t)r * 64 + cu];
    ax += bf_lo(q); ay += bf_hi(q);
  }
  red[tid] = make_float2(ax, ay);
  __syncthreads();
  if (rr == 0){
    #pragma unroll
    for (int p = 1; p < 4; p++){ float2 o = red[cu + (p << 6)]; ax += o.x; ay += o.y; }
    int c = s1 - s0; if (c < 1) c = 1;
    float inv = 1.0f / (float)c;
    pooled[g * DH + cu * 2]     = ax * inv;
    pooled[g * DH + cu * 2 + 1] = ay * inv;
  }
}
__global__ __launch_bounds__(128) void k_final(const float* pooled, const float* W_out,
                                               const float* b_out, float* out){
  __shared__ float pl[DH];
  int g = blockIdx.x, o = threadIdx.x;
  pl[o] = pooled[g * DH + o];
  __syncthreads();
  float acc = b_out[o];
  for (int k = 0; k < DH; ++k) acc += pl[k] * W_out[k * DO + o];
  out[g * DO + o] = acc;
}

extern "C" void kernel_launch(void* const* d_in, const int* in_sizes, int n_in,
                              void* d_out, int out_size, void* d_ws, size_t ws_size,
                              hipStream_t stream){
  const float* x         = (const float*)d_in[0];
  const int*   edge_index= (const int*)  d_in[1];
  const float* edge_attr = (const float*)d_in[2];
  const int*   batch     = (const int*)  d_in[3];
  const float* W_gcn     = (const float*)d_in[4];
  const float* b_gcn     = (const float*)d_in[5];
  const float* W_le      = (const float*)d_in[6];
  const float* b_le      = (const float*)d_in[7];
  const float* W_lin     = (const float*)d_in[8];
  const float* b_lin     = (const float*)d_in[9];
  const float* W_out     = (const float*)d_in[10];
  const float* b_out     = (const float*)d_in[11];
  float* out = (float*)d_out;

  const int n  = in_sizes[0] / DV;       // 100000
  const int e2 = in_sizes[1] / 2;        // 1600000 directed edges
  const int g  = out_size / DO;          // 64
  const int* srcp = edge_index;
  const int* dstp = edge_index + e2;
  const int e2pad = e2 + 7 * n + 8;      // CSR capacity with per-row pad-to-8

  char* ws = (char*)d_ws;
  size_t off = 0;
  auto alloc = [&](size_t bytes) -> char* {
    char* p = ws + off; off = (off + bytes + 255) & ~(size_t)255; return p;
  };

  int*   cnt     = (int*)  alloc((size_t)n * 4);
  int*   row_ptr = (int*)  alloc((size_t)(n + 1) * 4);
  int*   rank    = (int*)  alloc((size_t)e2 * 4);
  int*   partial = (int*)  alloc((size_t)n * 4);
  int*   bsums   = (int*)  alloc(512);
  int*   bexc    = (int*)  alloc(512);
  float* dinv    = (float*)alloc((size_t)n * 4);
  float* degf    = (float*)alloc((size_t)n * 4);
  int*   startg  = (int*)  alloc((size_t)(g + 1) * 4);
  float* pooled  = (float*)alloc((size_t)g * DH * 4);
  float* Wfull   = (float*)alloc(160 * DH * 4);
  u32*   h_b     = (u32*)  alloc((size_t)(n + 1) * 64 * 4);  // +1 zero row
  int2*  ce      = (int2*) alloc((size_t)e2pad * 8);
  u32*   h2_b    = (u32*)  alloc((size_t)n * 64 * 4);
  // region A: xws (bf16, [N+1,128]) later overwritten by A2 (bf16, [N,160])
  size_t szXW = (size_t)(n + 1) * 64 * 4, szA2 = (size_t)n * 160 * 2;
  char* regionA = alloc(szA2 > szXW ? szA2 : szXW);
  u32* xws_b = (u32*)regionA;
  u16* A2b   = (u16*)regionA;

  const int nb1024 = (n + 1023) / 1024;  // must be <= 128 for k_scan2

  k_init   <<<(n + 255) / 256, 256, 0, stream>>>(cnt, n);
  k_count  <<<(e2 + 255) / 256, 256, 0, stream>>>(dstp, cnt, rank, e2);
  k_scan1  <<<nb1024, 256, 0, stream>>>(cnt, partial, bsums, n);
  k_scan2  <<<1, 128, 0, stream>>>(bsums, bexc, nb1024);
  k_scan3  <<<(n + 255) / 256, 256, 0, stream>>>(partial, bexc, row_ptr, n);
  k_prep   <<<(n + 255) / 256, 256, 0, stream>>>(cnt, dinv, degf, n);
  k_scatter<<<(e2 + 255) / 256, 256, 0, stream>>>(srcp, dstp, rank, row_ptr, ce, e2);
  k_pad    <<<(n + 255) / 256, 256, 0, stream>>>(row_ptr, cnt, ce,
                                                 xws_b + (size_t)n * 64, h_b + (size_t)n * 64, n);
  k_wcombo <<<1, 128, 0, stream>>>(W_lin, b_lin, W_le, b_le, Wfull);

  k_gemm<DV, false, false, true><<<(n + 31) / 32, 256, 0, stream>>>(x, W_gcn, xws_b, dinv, n);
  k_phase1 <<<(n + 7) / 8, 256, 0, stream>>>(xws_b, row_ptr, ce, dinv, b_gcn, h_b, n);
  k_phase2 <<<(n + 7) / 8, 256, 0, stream>>>(h_b, row_ptr, ce, edge_attr, degf, A2b, n);
  k_gemm<160, true, true, false><<<(n + 31) / 32, 256, 0, stream>>>(A2b, Wfull, h2_b, (const float*)nullptr, n);

  k_starts <<<(n + 255) / 256, 256, 0, stream>>>(batch, startg, n, g);
  k_pool   <<<g, 256, 0, stream>>>(h2_b, startg, pooled, n);
  k_final  <<<g, 128, 0, stream>>>(pooled, W_out, b_out, out);
}

// Round 6
// 581.341 us; speedup vs baseline: 1.7105x; 1.1743x over previous
//
#include <hip/hip_runtime.h>
#include <hip/hip_bf16.h>
#include <cstddef>

typedef unsigned int  u32;
typedef unsigned short u16;

#define DV 128
#define DH 128
#define DE 16
#define DO 128
#define PSUB 32   // pooling sub-blocks per graph

// ---------- bf16 helpers (bit tricks, RNE) ----------
__device__ inline float bf_lo(u32 u){ return __uint_as_float(u << 16); }
__device__ inline float bf_hi(u32 u){ return __uint_as_float(u & 0xFFFF0000u); }
__device__ inline u32 fpack2(float a, float b){
  u32 ua = __float_as_uint(a), ub = __float_as_uint(b);
  ua += 0x7FFFu + ((ua >> 16) & 1u);
  ub += 0x7FFFu + ((ub >> 16) & 1u);
  return (ua >> 16) | (ub & 0xFFFF0000u);
}
__device__ inline u16 f2bf(float a){
  u32 ua = __float_as_uint(a); ua += 0x7FFFu + ((ua >> 16) & 1u); return (u16)(ua >> 16);
}

// ---------- CSR build ----------
__global__ void k_init(int* cnt, int n){
  int v = blockIdx.x * blockDim.x + threadIdx.x;
  if (v < n) cnt[v] = 0;
}
// count AND record each edge's rank within its dst bucket (coalesced store)
__global__ void k_count(const int* dst, int* cnt, int* rank, int e2){
  int j = blockIdx.x * blockDim.x + threadIdx.x;
  if (j < e2) rank[j] = atomicAdd(&cnt[dst[j]], 1);
}
// scan of PADDED counts: pc = (cnt+7)&~7  (rows padded to multiple of 8)
__global__ __launch_bounds__(256) void k_scan1(const int* cnt, int* partial, int* bsums, int n){
  __shared__ int lds[256];
  int t = threadIdx.x;
  int base = blockIdx.x * 1024 + t * 4;
  int v0=0,v1=0,v2=0,v3=0;
  if (base + 3 < n){ int4 q = *(const int4*)(cnt + base); v0=q.x; v1=q.y; v2=q.z; v3=q.w; }
  else {
    if (base + 0 < n) v0 = cnt[base];
    if (base + 1 < n) v1 = cnt[base+1];
    if (base + 2 < n) v2 = cnt[base+2];
  }
  v0 = (v0 + 7) & ~7; v1 = (v1 + 7) & ~7; v2 = (v2 + 7) & ~7; v3 = (v3 + 7) & ~7;
  v1 += v0; v2 += v1; v3 += v2;
  lds[t] = v3; __syncthreads();
  for (int off = 1; off < 256; off <<= 1){
    int x = (t >= off) ? lds[t - off] : 0;
    __syncthreads();
    lds[t] += x;
    __syncthreads();
  }
  int add = (t > 0) ? lds[t - 1] : 0;
  if (base + 3 < n){
    int4 q; q.x = v0+add; q.y = v1+add; q.z = v2+add; q.w = v3+add;
    *(int4*)(partial + base) = q;
  } else {
    if (base + 0 < n) partial[base]   = v0 + add;
    if (base + 1 < n) partial[base+1] = v1 + add;
    if (base + 2 < n) partial[base+2] = v2 + add;
  }
  if (t == 255) bsums[blockIdx.x] = lds[255];
}
__global__ void k_scan2(const int* bsums, int* bexc, int nb){
  __shared__ int lds[128];
  int t = threadIdx.x;
  lds[t] = (t < nb) ? bsums[t] : 0;
  __syncthreads();
  for (int off = 1; off < 128; off <<= 1){
    int x = (t >= off) ? lds[t - off] : 0;
    __syncthreads();
    lds[t] += x;
    __syncthreads();
  }
  if (t < nb) bexc[t] = (t > 0) ? lds[t - 1] : 0;
}
__global__ void k_scan3(const int* partial, const int* bexc, int* row_ptr, int n){
  int i = blockIdx.x * blockDim.x + threadIdx.x;
  if (i < n) row_ptr[i + 1] = partial[i] + bexc[i >> 10];
  if (i == 0) row_ptr[0] = 0;
}
__global__ void k_prep(const int* cnt, float* dinv, float* degf, int n){
  int v = blockIdx.x * blockDim.x + threadIdx.x;
  if (v < n){
    float c = (float)(cnt[v] + 1);   // in-degree + self-loop
    dinv[v] = rsqrtf(c);
    degf[v] = c;
  }
}
// scatter WITHOUT atomic: pos = row_ptr[dst] + precomputed rank
__global__ void k_scatter(const int* src, const int* dst, const int* rank,
                          const int* row_ptr, int2* ce, int e2){
  int j = blockIdx.x * blockDim.x + threadIdx.x;
  if (j < e2){
    int d = dst[j];
    int pos = row_ptr[d] + rank[j];
    ce[pos] = make_int2(src[j], j);
  }
}
// fill CSR pad slots with {n, 0}; zero the gather tables' row n
__global__ void k_pad(const int* row_ptr, const int* cnt, int2* ce,
                      u32* xws_zrow, u32* h_zrow, int n){
  int v = blockIdx.x * blockDim.x + threadIdx.x;
  if (v < n){
    int s = row_ptr[v] + cnt[v], e = row_ptr[v + 1];
    for (int i = s; i < e; ++i) ce[i] = make_int2(n, 0);
  }
  if (blockIdx.x == 0 && threadIdx.x < 64){
    xws_zrow[threadIdx.x] = 0u;
    h_zrow[threadIdx.x] = 0u;
  }
}

// ---------- fold W_le@W_bot and biases into the h2 GEMM weight ----------
__global__ __launch_bounds__(128) void k_wcombo(const float* W_lin, const float* b_lin,
                                                const float* W_le, const float* b_le, float* Wfull){
  __shared__ float wle[DE * DH];
  int c = threadIdx.x;
  for (int i = c; i < DE * DH; i += 128) wle[i] = W_le[i];
  __syncthreads();
  float combo[DE];
  #pragma unroll
  for (int i = 0; i < DE; i++) combo[i] = 0.f;
  float bacc = b_lin[c];
  for (int k = 0; k < DH; ++k){
    float wv = W_lin[(size_t)(DH + k) * DH + c];   // W_bot[k][c]
    bacc += b_le[k] * wv;
    #pragma unroll
    for (int i = 0; i < DE; i++) combo[i] += wle[i * DH + k] * wv;
  }
  for (int r = 0; r < DH; ++r) Wfull[r * DH + c] = W_lin[r * DH + c];
  #pragma unroll
  for (int i = 0; i < DE; i++) Wfull[(DH + i) * DH + c] = combo[i];
  Wfull[144 * DH + c] = bacc;
  for (int r = 145; r < 160; ++r) Wfull[r * DH + c] = 0.f;
}

// ---------- register-tiled GEMM: [M,K] @ [K,128] -> bf16-packed out ----------
template<int K, bool RELU, bool ABF16, bool SCALE>
__global__ __launch_bounds__(256) void k_gemm(const void* Ap, const float* W, u32* outb,
                                              const float* scale, int M){
  __shared__ float Ws[32][128];
  __shared__ float At[32][36];
  int tid = threadIdx.x;
  int row0 = blockIdx.x * 32;
  int tc = tid & 31, tr = tid >> 5;
  int c0 = tc * 4, r0 = tr * 4;
  float acc[4][4];
  #pragma unroll
  for (int i = 0; i < 4; i++)
    #pragma unroll
    for (int j = 0; j < 4; j++) acc[i][j] = 0.f;
  int lr = tid >> 3;
  int lk = (tid & 7) * 4;
  for (int kc = 0; kc < K; kc += 32){
    int gr = row0 + lr; if (gr > M - 1) gr = M - 1;
    if (ABF16){
      const u16* A = (const u16*)Ap;
      uint2 q = *(const uint2*)(A + (size_t)gr * K + kc + lk);
      At[lk+0][lr] = bf_lo(q.x); At[lk+1][lr] = bf_hi(q.x);
      At[lk+2][lr] = bf_lo(q.y); At[lk+3][lr] = bf_hi(q.y);
    } else {
      const float* A = (const float*)Ap;
      float4 q = *(const float4*)(A + (size_t)gr * K + kc + lk);
      At[lk+0][lr] = q.x; At[lk+1][lr] = q.y; At[lk+2][lr] = q.z; At[lk+3][lr] = q.w;
    }
    {
      int c4 = (tid & 31) * 4, kb = tid >> 5;
      #pragma unroll
      for (int p = 0; p < 4; p++){
        int kr = kb + p * 8;
        *(float4*)&Ws[kr][c4] = *(const float4*)(W + (size_t)(kc + kr) * DH + c4);
      }
    }
    __syncthreads();
    #pragma unroll
    for (int kk = 0; kk < 32; ++kk){
      float4 w = *(const float4*)&Ws[kk][c0];
      float4 a = *(const float4*)&At[kk][r0];
      acc[0][0] += a.x*w.x; acc[0][1] += a.x*w.y; acc[0][2] += a.x*w.z; acc[0][3] += a.x*w.w;
      acc[1][0] += a.y*w.x; acc[1][1] += a.y*w.y; acc[1][2] += a.y*w.z; acc[1][3] += a.y*w.w;
      acc[2][0] += a.z*w.x; acc[2][1] += a.z*w.y; acc[2][2] += a.z*w.z; acc[2][3] += a.z*w.w;
      acc[3][0] += a.w*w.x; acc[3][1] += a.w*w.y; acc[3][2] += a.w*w.z; acc[3][3] += a.w*w.w;
    }
    __syncthreads();
  }
  #pragma unroll
  for (int i = 0; i < 4; i++){
    int r = row0 + r0 + i;
    if (r < M){
      float x0 = acc[i][0], x1 = acc[i][1], x2 = acc[i][2], x3 = acc[i][3];
      if (SCALE){
        float sc = scale[r];
        x0 *= sc; x1 *= sc; x2 *= sc; x3 *= sc;
      }
      if (RELU){ x0 = fmaxf(x0, 0.f); x1 = fmaxf(x1, 0.f); x2 = fmaxf(x2, 0.f); x3 = fmaxf(x3, 0.f); }
      uint2 o; o.x = fpack2(x0, x1); o.y = fpack2(x2, x3);
      *(uint2*)(outb + (size_t)r * 64 + tc * 2) = o;
    }
  }
}

// ---------- phase 1: 2 nodes per wave (32 lanes x uint2 each), 16 gathers in flight ----------
__global__ __launch_bounds__(256) void k_phase1(const u32* xws, const int* row_ptr, const int2* ce,
                                                const float* dinv, const float* b_gcn, u32* h_b, int n){
  int lane = threadIdx.x & 63;
  int ln = lane & 31;
  int v = blockIdx.x * 8 + ((threadIdx.x >> 6) << 1) + (lane >> 5);
  if (v >= n) return;
  uint2 sp = *(const uint2*)(xws + (size_t)v * 64 + ln * 2);
  float a0 = bf_lo(sp.x), a1 = bf_hi(sp.x), a2 = bf_lo(sp.y), a3 = bf_hi(sp.y);
  int e0 = row_ptr[v], e1 = row_ptr[v + 1];
  for (int i = e0; i < e1; i += 8){
    const int4* cp = (const int4*)(ce + i);
    int4 A = cp[0], B = cp[1], C = cp[2], D = cp[3];
    uint2 q0 = *(const uint2*)(xws + (size_t)A.x * 64 + ln * 2);
    uint2 q1 = *(const uint2*)(xws + (size_t)A.z * 64 + ln * 2);
    uint2 q2 = *(const uint2*)(xws + (size_t)B.x * 64 + ln * 2);
    uint2 q3 = *(const uint2*)(xws + (size_t)B.z * 64 + ln * 2);
    uint2 q4 = *(const uint2*)(xws + (size_t)C.x * 64 + ln * 2);
    uint2 q5 = *(const uint2*)(xws + (size_t)C.z * 64 + ln * 2);
    uint2 q6 = *(const uint2*)(xws + (size_t)D.x * 64 + ln * 2);
    uint2 q7 = *(const uint2*)(xws + (size_t)D.z * 64 + ln * 2);
    a0 += ((bf_lo(q0.x) + bf_lo(q1.x)) + (bf_lo(q2.x) + bf_lo(q3.x)))
        + ((bf_lo(q4.x) + bf_lo(q5.x)) + (bf_lo(q6.x) + bf_lo(q7.x)));
    a1 += ((bf_hi(q0.x) + bf_hi(q1.x)) + (bf_hi(q2.x) + bf_hi(q3.x)))
        + ((bf_hi(q4.x) + bf_hi(q5.x)) + (bf_hi(q6.x) + bf_hi(q7.x)));
    a2 += ((bf_lo(q0.y) + bf_lo(q1.y)) + (bf_lo(q2.y) + bf_lo(q3.y)))
        + ((bf_lo(q4.y) + bf_lo(q5.y)) + (bf_lo(q6.y) + bf_lo(q7.y)));
    a3 += ((bf_hi(q0.y) + bf_hi(q1.y)) + (bf_hi(q2.y) + bf_hi(q3.y)))
        + ((bf_hi(q4.y) + bf_hi(q5.y)) + (bf_hi(q6.y) + bf_hi(q7.y)));
  }
  float dv = dinv[v];
  float4 bg = *(const float4*)(b_gcn + ln * 4);
  a0 = fmaxf(fmaf(dv, a0, bg.x), 0.f);
  a1 = fmaxf(fmaf(dv, a1, bg.y), 0.f);
  a2 = fmaxf(fmaf(dv, a2, bg.z), 0.f);
  a3 = fmaxf(fmaf(dv, a3, bg.w), 0.f);
  uint2 o; o.x = fpack2(a0, a1); o.y = fpack2(a2, a3);
  *(uint2*)(h_b + (size_t)v * 64 + ln * 2) = o;
}

// ---------- phase 2: 2 nodes per wave; aggx gather + ea gather ----------
__global__ __launch_bounds__(256) void k_phase2(const u32* h_b, const int* row_ptr, const int2* ce,
                                                const float* edge_attr, const float* degf,
                                                u16* A2b, int n){
  int lane = threadIdx.x & 63;
  int ln = lane & 31;
  int half = lane >> 5;
  int v = blockIdx.x * 8 + ((threadIdx.x >> 6) << 1) + half;
  if (v >= n) return;
  uint2 sp = *(const uint2*)(h_b + (size_t)v * 64 + ln * 2);
  float a0 = bf_lo(sp.x), a1 = bf_hi(sp.x), a2 = bf_lo(sp.y), a3 = bf_hi(sp.y);
  float es = 0.f;                  // channel ln&15, slot-group ln>>4 (4 edges each)
  int ch = ln & 15, grp = ln >> 4;
  int e0 = row_ptr[v], e1 = row_ptr[v + 1];
  for (int i = e0; i < e1; i += 8){
    const int4* cp = (const int4*)(ce + i);
    int4 A = cp[0], B = cp[1], C = cp[2], D = cp[3];
    int gb = i + grp * 4;
    int2 c0 = ce[gb + 0];
    int2 c1 = ce[gb + 1];
    int2 c2 = ce[gb + 2];
    int2 c3 = ce[gb + 3];
    uint2 q0 = *(const uint2*)(h_b + (size_t)A.x * 64 + ln * 2);
    uint2 q1 = *(const uint2*)(h_b + (size_t)A.z * 64 + ln * 2);
    uint2 q2 = *(const uint2*)(h_b + (size_t)B.x * 64 + ln * 2);
    uint2 q3 = *(const uint2*)(h_b + (size_t)B.z * 64 + ln * 2);
    uint2 q4 = *(const uint2*)(h_b + (size_t)C.x * 64 + ln * 2);
    uint2 q5 = *(const uint2*)(h_b + (size_t)C.z * 64 + ln * 2);
    uint2 q6 = *(const uint2*)(h_b + (size_t)D.x * 64 + ln * 2);
    uint2 q7 = *(const uint2*)(h_b + (size_t)D.z * 64 + ln * 2);
    float m0 = (c0.x != n) ? 1.f : 0.f;
    float m1 = (c1.x != n) ? 1.f : 0.f;
    float m2 = (c2.x != n) ? 1.f : 0.f;
    float m3 = (c3.x != n) ? 1.f : 0.f;
    float v0 = edge_attr[(size_t)(c0.y >> 1) * DE + ch];
    float v1 = edge_attr[(size_t)(c1.y >> 1) * DE + ch];
    float v2 = edge_attr[(size_t)(c2.y >> 1) * DE + ch];
    float v3 = edge_attr[(size_t)(c3.y >> 1) * DE + ch];
    es = fmaf(m0, v0, es);
    es = fmaf(m1, v1, es);
    es = fmaf(m2, v2, es);
    es = fmaf(m3, v3, es);
    a0 += ((bf_lo(q0.x) + bf_lo(q1.x)) + (bf_lo(q2.x) + bf_lo(q3.x)))
        + ((bf_lo(q4.x) + bf_lo(q5.x)) + (bf_lo(q6.x) + bf_lo(q7.x)));
    a1 += ((bf_hi(q0.x) + bf_hi(q1.x)) + (bf_hi(q2.x) + bf_hi(q3.x)))
        + ((bf_hi(q4.x) + bf_hi(q5.x)) + (bf_hi(q6.x) + bf_hi(q7.x)));
    a2 += ((bf_lo(q0.y) + bf_lo(q1.y)) + (bf_lo(q2.y) + bf_lo(q3.y)))
        + ((bf_lo(q4.y) + bf_lo(q5.y)) + (bf_lo(q6.y) + bf_lo(q7.y)));
    a3 += ((bf_hi(q0.y) + bf_hi(q1.y)) + (bf_hi(q2.y) + bf_hi(q3.y)))
        + ((bf_hi(q4.y) + bf_hi(q5.y)) + (bf_hi(q6.y) + bf_hi(q7.y)));
  }
  // within-half reduction over the 2 slot groups, then wave-uniform pair pick
  es += __shfl_xor(es, 16);
  float c0v = __shfl(es, half * 32 + (ln & 7) * 2);
  float c1v = __shfl(es, half * 32 + (ln & 7) * 2 + 1);
  u32* rowp = (u32*)(A2b + (size_t)v * 160);
  uint2 o; o.x = fpack2(a0, a1); o.y = fpack2(a2, a3);
  *(uint2*)(rowp + ln * 2) = o;
  if (ln < 8){
    rowp[64 + ln] = fpack2(c0v + 1.0f, c1v + 1.0f);
  } else if (ln < 16){
    rowp[64 + ln] = (ln == 8) ? (u32)f2bf(degf[v]) : 0u;
  }
}

// ---------- pooling ----------
__global__ void k_starts(const int* batch, int* start, int n, int g){
  int v = blockIdx.x * blockDim.x + threadIdx.x;
  if (v >= n) return;
  int b = batch[v];
  int prev = (v == 0) ? -1 : batch[v - 1];
  for (int q = prev + 1; q <= b; ++q) start[q] = v;
  if (v == n - 1){ for (int q = b + 1; q <= g; ++q) start[q] = n; }
}
// stage A: (graph, sub) blocks; 32 sub-blocks per graph for occupancy
__global__ __launch_bounds__(256) void k_pool_a(const u32* h2_b, const int* start, float* partialp){
  __shared__ float2 red[256];
  int g = blockIdx.x >> 5;
  int s = blockIdx.x & (PSUB - 1);
  int s0 = start[g], s1 = start[g + 1];
  int tid = threadIdx.x;
  int cu = tid & 63, rr = tid >> 6;
  float ax = 0.f, ay = 0.f;
  for (int r = s0 + s * 4 + rr; r < s1; r += PSUB * 4){
    u32 q = h2_b[(size_t)r * 64 + cu];
    ax += bf_lo(q); ay += bf_hi(q);
  }
  red[tid] = make_float2(ax, ay);
  __syncthreads();
  if (rr == 0){
    #pragma unroll
    for (int p = 1; p < 4; p++){ float2 o = red[cu + (p << 6)]; ax += o.x; ay += o.y; }
    *(float2*)(partialp + (size_t)blockIdx.x * 128 + cu * 2) = make_float2(ax, ay);
  }
}
// stage B fused with final linear: reduce 32 partials, mean, @ W_out + b_out
__global__ __launch_bounds__(128) void k_poolb_final(const float* partialp, const int* start,
                                                     const float* W_out, const float* b_out,
                                                     float* out){
  __shared__ float pl[DH];
  int g = blockIdx.x, c = threadIdx.x;
  float sum = 0.f;
  #pragma unroll 4
  for (int s = 0; s < PSUB; ++s) sum += partialp[((size_t)g * PSUB + s) * 128 + c];
  int cntg = start[g + 1] - start[g]; if (cntg < 1) cntg = 1;
  pl[c] = sum / (float)cntg;
  __syncthreads();
  float acc = b_out[c];
  for (int k = 0; k < DH; ++k) acc += pl[k] * W_out[k * DO + c];
  out[g * DO + c] = acc;
}

extern "C" void kernel_launch(void* const* d_in, const int* in_sizes, int n_in,
                              void* d_out, int out_size, void* d_ws, size_t ws_size,
                              hipStream_t stream){
  const float* x         = (const float*)d_in[0];
  const int*   edge_index= (const int*)  d_in[1];
  const float* edge_attr = (const float*)d_in[2];
  const int*   batch     = (const int*)  d_in[3];
  const float* W_gcn     = (const float*)d_in[4];
  const float* b_gcn     = (const float*)d_in[5];
  const float* W_le      = (const float*)d_in[6];
  const float* b_le      = (const float*)d_in[7];
  const float* W_lin     = (const float*)d_in[8];
  const float* b_lin     = (const float*)d_in[9];
  const float* W_out     = (const float*)d_in[10];
  const float* b_out     = (const float*)d_in[11];
  float* out = (float*)d_out;

  const int n  = in_sizes[0] / DV;       // 100000
  const int e2 = in_sizes[1] / 2;        // 1600000 directed edges
  const int g  = out_size / DO;          // 64
  const int* srcp = edge_index;
  const int* dstp = edge_index + e2;
  const int e2pad = e2 + 7 * n + 8;      // CSR capacity with per-row pad-to-8

  char* ws = (char*)d_ws;
  size_t off = 0;
  auto alloc = [&](size_t bytes) -> char* {
    char* p = ws + off; off = (off + bytes + 255) & ~(size_t)255; return p;
  };

  int*   cnt     = (int*)  alloc((size_t)n * 4);
  int*   row_ptr = (int*)  alloc((size_t)(n + 1) * 4);
  int*   rank    = (int*)  alloc((size_t)e2 * 4);
  int*   partial = (int*)  alloc((size_t)n * 4);
  int*   bsums   = (int*)  alloc(512);
  int*   bexc    = (int*)  alloc(512);
  float* dinv    = (float*)alloc((size_t)n * 4);
  float* degf    = (float*)alloc((size_t)n * 4);
  int*   startg  = (int*)  alloc((size_t)(g + 1) * 4);
  float* partialp= (float*)alloc((size_t)g * PSUB * 128 * 4);
  float* Wfull   = (float*)alloc(160 * DH * 4);
  u32*   h_b     = (u32*)  alloc((size_t)(n + 1) * 64 * 4);  // +1 zero row
  int2*  ce      = (int2*) alloc((size_t)e2pad * 8);
  u32*   h2_b    = (u32*)  alloc((size_t)n * 64 * 4);
  // region A: xws (bf16, [N+1,128]) later overwritten by A2 (bf16, [N,160])
  size_t szXW = (size_t)(n + 1) * 64 * 4, szA2 = (size_t)n * 160 * 2;
  char* regionA = alloc(szA2 > szXW ? szA2 : szXW);
  u32* xws_b = (u32*)regionA;
  u16* A2b   = (u16*)regionA;

  const int nb1024 = (n + 1023) / 1024;  // must be <= 128 for k_scan2

  k_init   <<<(n + 255) / 256, 256, 0, stream>>>(cnt, n);
  k_count  <<<(e2 + 255) / 256, 256, 0, stream>>>(dstp, cnt, rank, e2);
  k_scan1  <<<nb1024, 256, 0, stream>>>(cnt, partial, bsums, n);
  k_scan2  <<<1, 128, 0, stream>>>(bsums, bexc, nb1024);
  k_scan3  <<<(n + 255) / 256, 256, 0, stream>>>(partial, bexc, row_ptr, n);
  k_prep   <<<(n + 255) / 256, 256, 0, stream>>>(cnt, dinv, degf, n);
  k_scatter<<<(e2 + 255) / 256, 256, 0, stream>>>(srcp, dstp, rank, row_ptr, ce, e2);
  k_pad    <<<(n + 255) / 256, 256, 0, stream>>>(row_ptr, cnt, ce,
                                                 xws_b + (size_t)n * 64, h_b + (size_t)n * 64, n);
  k_wcombo <<<1, 128, 0, stream>>>(W_lin, b_lin, W_le, b_le, Wfull);

  k_gemm<DV, false, false, true><<<(n + 31) / 32, 256, 0, stream>>>(x, W_gcn, xws_b, dinv, n);
  k_phase1 <<<(n + 7) / 8, 256, 0, stream>>>(xws_b, row_ptr, ce, dinv, b_gcn, h_b, n);
  k_phase2 <<<(n + 7) / 8, 256, 0, stream>>>(h_b, row_ptr, ce, edge_attr, degf, A2b, n);
  k_gemm<160, true, true, false><<<(n + 31) / 32, 256, 0, stream>>>(A2b, Wfull, h2_b, (const float*)nullptr, n);

  k_starts      <<<(n + 255) / 256, 256, 0, stream>>>(batch, startg, n, g);
  k_pool_a      <<<g * PSUB, 256, 0, stream>>>(h2_b, startg, partialp);
  k_poolb_final <<<g, 128, 0, stream>>>(partialp, startg, W_out, b_out, out);
}

// Round 7
// 530.916 us; speedup vs baseline: 1.8730x; 1.0950x over previous
//
#include <hip/hip_runtime.h>
#include <hip/hip_bf16.h>
#include <cstddef>

typedef unsigned int  u32;
typedef unsigned short u16;
typedef __attribute__((ext_vector_type(8))) short short8;
typedef __attribute__((ext_vector_type(4))) float f32x4;

#define DV 128
#define DH 128
#define DE 16
#define DO 128
#define PSUB 32   // pooling sub-blocks per graph

// ---------- bf16 helpers (bit tricks, RNE) ----------
__device__ inline float bf_lo(u32 u){ return __uint_as_float(u << 16); }
__device__ inline float bf_hi(u32 u){ return __uint_as_float(u & 0xFFFF0000u); }
__device__ inline u32 fpack2(float a, float b){
  u32 ua = __float_as_uint(a), ub = __float_as_uint(b);
  ua += 0x7FFFu + ((ua >> 16) & 1u);
  ub += 0x7FFFu + ((ub >> 16) & 1u);
  return (ua >> 16) | (ub & 0xFFFF0000u);
}
__device__ inline u16 f2bf(float a){
  u32 ua = __float_as_uint(a); ua += 0x7FFFu + ((ua >> 16) & 1u); return (u16)(ua >> 16);
}

// ---------- CSR build ----------
__global__ void k_init(int* cnt, int n){
  int v = blockIdx.x * blockDim.x + threadIdx.x;
  if (v < n) cnt[v] = 0;
}
// count AND record each edge's rank within its dst bucket (coalesced store)
__global__ void k_count(const int* dst, int* cnt, int* rank, int e2){
  int j = blockIdx.x * blockDim.x + threadIdx.x;
  if (j < e2) rank[j] = atomicAdd(&cnt[dst[j]], 1);
}
// scan of PADDED counts: pc = (cnt+7)&~7  (rows padded to multiple of 8)
__global__ __launch_bounds__(256) void k_scan1(const int* cnt, int* partial, int* bsums, int n){
  __shared__ int lds[256];
  int t = threadIdx.x;
  int base = blockIdx.x * 1024 + t * 4;
  int v0=0,v1=0,v2=0,v3=0;
  if (base + 3 < n){ int4 q = *(const int4*)(cnt + base); v0=q.x; v1=q.y; v2=q.z; v3=q.w; }
  else {
    if (base + 0 < n) v0 = cnt[base];
    if (base + 1 < n) v1 = cnt[base+1];
    if (base + 2 < n) v2 = cnt[base+2];
  }
  v0 = (v0 + 7) & ~7; v1 = (v1 + 7) & ~7; v2 = (v2 + 7) & ~7; v3 = (v3 + 7) & ~7;
  v1 += v0; v2 += v1; v3 += v2;
  lds[t] = v3; __syncthreads();
  for (int off = 1; off < 256; off <<= 1){
    int x = (t >= off) ? lds[t - off] : 0;
    __syncthreads();
    lds[t] += x;
    __syncthreads();
  }
  int add = (t > 0) ? lds[t - 1] : 0;
  if (base + 3 < n){
    int4 q; q.x = v0+add; q.y = v1+add; q.z = v2+add; q.w = v3+add;
    *(int4*)(partial + base) = q;
  } else {
    if (base + 0 < n) partial[base]   = v0 + add;
    if (base + 1 < n) partial[base+1] = v1 + add;
    if (base + 2 < n) partial[base+2] = v2 + add;
  }
  if (t == 255) bsums[blockIdx.x] = lds[255];
}
__global__ void k_scan2(const int* bsums, int* bexc, int nb){
  __shared__ int lds[128];
  int t = threadIdx.x;
  lds[t] = (t < nb) ? bsums[t] : 0;
  __syncthreads();
  for (int off = 1; off < 128; off <<= 1){
    int x = (t >= off) ? lds[t - off] : 0;
    __syncthreads();
    lds[t] += x;
    __syncthreads();
  }
  if (t < nb) bexc[t] = (t > 0) ? lds[t - 1] : 0;
}
__global__ void k_scan3(const int* partial, const int* bexc, int* row_ptr, int n){
  int i = blockIdx.x * blockDim.x + threadIdx.x;
  if (i < n) row_ptr[i + 1] = partial[i] + bexc[i >> 10];
  if (i == 0) row_ptr[0] = 0;
}
__global__ void k_prep(const int* cnt, float* dinv, float* degf, int n){
  int v = blockIdx.x * blockDim.x + threadIdx.x;
  if (v < n){
    float c = (float)(cnt[v] + 1);   // in-degree + self-loop
    dinv[v] = rsqrtf(c);
    degf[v] = c;
  }
}
// scatter WITHOUT atomic: pos = row_ptr[dst] + precomputed rank
__global__ void k_scatter(const int* src, const int* dst, const int* rank,
                          const int* row_ptr, int2* ce, int e2){
  int j = blockIdx.x * blockDim.x + threadIdx.x;
  if (j < e2){
    int d = dst[j];
    int pos = row_ptr[d] + rank[j];
    ce[pos] = make_int2(src[j], j);
  }
}
// fill CSR pad slots with {n, 0}; zero the gather tables' row n
__global__ void k_pad(const int* row_ptr, const int* cnt, int2* ce,
                      u32* xws_zrow, u32* h_zrow, int n){
  int v = blockIdx.x * blockDim.x + threadIdx.x;
  if (v < n){
    int s = row_ptr[v] + cnt[v], e = row_ptr[v + 1];
    for (int i = s; i < e; ++i) ce[i] = make_int2(n, 0);
  }
  if (blockIdx.x == 0 && threadIdx.x < 64){
    xws_zrow[threadIdx.x] = 0u;
    h_zrow[threadIdx.x] = 0u;
  }
}

// ---------- fold W_le@W_bot and biases into the h2 GEMM weight ----------
__global__ __launch_bounds__(128) void k_wcombo(const float* W_lin, const float* b_lin,
                                                const float* W_le, const float* b_le, float* Wfull){
  __shared__ float wle[DE * DH];
  int c = threadIdx.x;
  for (int i = c; i < DE * DH; i += 128) wle[i] = W_le[i];
  __syncthreads();
  float combo[DE];
  #pragma unroll
  for (int i = 0; i < DE; i++) combo[i] = 0.f;
  float bacc = b_lin[c];
  for (int k = 0; k < DH; ++k){
    float wv = W_lin[(size_t)(DH + k) * DH + c];   // W_bot[k][c]
    bacc += b_le[k] * wv;
    #pragma unroll
    for (int i = 0; i < DE; i++) combo[i] += wle[i * DH + k] * wv;
  }
  for (int r = 0; r < DH; ++r) Wfull[r * DH + c] = W_lin[r * DH + c];
  #pragma unroll
  for (int i = 0; i < DE; i++) Wfull[(DH + i) * DH + c] = combo[i];
  Wfull[144 * DH + c] = bacc;
  for (int r = 145; r < 160; ++r) Wfull[r * DH + c] = 0.f;
}

// ---------- MFMA GEMM: [M,K] @ [K,128] -> bf16-packed out ----------
// block = 256 (4 waves), tile 64 rows x 128 cols; v_mfma_f32_16x16x32_bf16.
// Frag layouts (m89/m91-verified): A/B lane l holds free-index l&15,
// k = (l>>4)*8 + j (8 consecutive); C/D col=l&15, row=(l>>4)*4+reg.
template<int K, bool RELU, bool ABF16, bool SCALE>
__global__ __launch_bounds__(256) void k_gemm_mfma(const void* Ap, const float* W, u32* outb,
                                                   const float* scale, int M){
  constexpr int SA = K + 8;      // u16 stride (16-B aligned rows, conflict-mitigating)
  constexpr int CS = 136;        // Ct stride (u16)
  __shared__ u16 Wt[128 * SA];   // W transposed, bf16: Wt[c][k]
  __shared__ u16 At[64 * SA];    // A tile bf16 (reused as Ct in epilogue)
  int tid = threadIdx.x;
  int row0 = blockIdx.x * 64;

  // ---- stage Wt: coalesced fp32 reads, transposed bf16x8 LDS writes ----
  {
    int c = tid & 127, half = tid >> 7;
    for (int g = half; g < K / 8; g += 2){
      int k0 = g * 8;
      float w0 = W[(size_t)(k0+0)*128 + c], w1 = W[(size_t)(k0+1)*128 + c];
      float w2 = W[(size_t)(k0+2)*128 + c], w3 = W[(size_t)(k0+3)*128 + c];
      float w4 = W[(size_t)(k0+4)*128 + c], w5 = W[(size_t)(k0+5)*128 + c];
      float w6 = W[(size_t)(k0+6)*128 + c], w7 = W[(size_t)(k0+7)*128 + c];
      uint4 pk;
      pk.x = fpack2(w0, w1); pk.y = fpack2(w2, w3);
      pk.z = fpack2(w4, w5); pk.w = fpack2(w6, w7);
      *(uint4*)&Wt[c * SA + k0] = pk;
    }
  }
  // ---- stage At ----
  constexpr int CH = K / 8;
  for (int idx = tid; idx < 64 * CH; idx += 256){
    int r = idx / CH, ch = idx - r * CH;
    int gr = row0 + r; if (gr > M - 1) gr = M - 1;
    uint4 pk;
    if (ABF16){
      pk = *(const uint4*)((const u16*)Ap + (size_t)gr * K + ch * 8);
    } else {
      const float* A = (const float*)Ap + (size_t)gr * K + ch * 8;
      float4 q0 = *(const float4*)A;
      float4 q1 = *(const float4*)(A + 4);
      pk.x = fpack2(q0.x, q0.y); pk.y = fpack2(q0.z, q0.w);
      pk.z = fpack2(q1.x, q1.y); pk.w = fpack2(q1.z, q1.w);
    }
    *(uint4*)&At[r * SA + ch * 8] = pk;
  }
  __syncthreads();

  // ---- MFMA main loop ----
  int l = tid & 63, w = tid >> 6;
  int m = l & 15, quad = l >> 4;
  f32x4 acc[8];
  #pragma unroll
  for (int ct = 0; ct < 8; ++ct) acc[ct] = (f32x4){0.f, 0.f, 0.f, 0.f};
  #pragma unroll
  for (int ks = 0; ks < K; ks += 32){
    short8 av = *(const short8*)&At[(w * 16 + m) * SA + ks + quad * 8];
    #pragma unroll
    for (int ct = 0; ct < 8; ++ct){
      short8 bv = *(const short8*)&Wt[(ct * 16 + m) * SA + ks + quad * 8];
      acc[ct] = __builtin_amdgcn_mfma_f32_16x16x32_bf16(av, bv, acc[ct], 0, 0, 0);
    }
  }
  __syncthreads();   // done reading At — reuse as Ct

  // ---- epilogue: scale/relu, bf16 pack into Ct, coalesced store ----
  u16* Ct = At;
  float sc[4];
  if (SCALE){
    #pragma unroll
    for (int r = 0; r < 4; ++r){
      int gr = row0 + w * 16 + quad * 4 + r;
      sc[r] = scale[gr < M ? gr : (M - 1)];
    }
  }
  #pragma unroll
  for (int ct = 0; ct < 8; ++ct){
    #pragma unroll
    for (int r = 0; r < 4; ++r){
      float vv = acc[ct][r];
      if (SCALE) vv *= sc[r];
      if (RELU)  vv = fmaxf(vv, 0.f);
      Ct[(w * 16 + quad * 4 + r) * CS + ct * 16 + m] = f2bf(vv);
    }
  }
  __syncthreads();
  for (int idx = tid; idx < 64 * 16; idx += 256){
    int r = idx >> 4, ch = idx & 15;
    int gr = row0 + r;
    if (gr < M){
      uint4 q = *(const uint4*)&Ct[r * CS + ch * 8];
      *(uint4*)(outb + (size_t)gr * 64 + ch * 4) = q;
    }
  }
}

// ---------- phase 1: 2 nodes per wave (32 lanes x uint2 each), 16 gathers in flight ----------
__global__ __launch_bounds__(256) void k_phase1(const u32* xws, const int* row_ptr, const int2* ce,
                                                const float* dinv, const float* b_gcn, u32* h_b, int n){
  int lane = threadIdx.x & 63;
  int ln = lane & 31;
  int v = blockIdx.x * 8 + ((threadIdx.x >> 6) << 1) + (lane >> 5);
  if (v >= n) return;
  uint2 sp = *(const uint2*)(xws + (size_t)v * 64 + ln * 2);
  float a0 = bf_lo(sp.x), a1 = bf_hi(sp.x), a2 = bf_lo(sp.y), a3 = bf_hi(sp.y);
  int e0 = row_ptr[v], e1 = row_ptr[v + 1];
  for (int i = e0; i < e1; i += 8){
    const int4* cp = (const int4*)(ce + i);
    int4 A = cp[0], B = cp[1], C = cp[2], D = cp[3];
    uint2 q0 = *(const uint2*)(xws + (size_t)A.x * 64 + ln * 2);
    uint2 q1 = *(const uint2*)(xws + (size_t)A.z * 64 + ln * 2);
    uint2 q2 = *(const uint2*)(xws + (size_t)B.x * 64 + ln * 2);
    uint2 q3 = *(const uint2*)(xws + (size_t)B.z * 64 + ln * 2);
    uint2 q4 = *(const uint2*)(xws + (size_t)C.x * 64 + ln * 2);
    uint2 q5 = *(const uint2*)(xws + (size_t)C.z * 64 + ln * 2);
    uint2 q6 = *(const uint2*)(xws + (size_t)D.x * 64 + ln * 2);
    uint2 q7 = *(const uint2*)(xws + (size_t)D.z * 64 + ln * 2);
    a0 += ((bf_lo(q0.x) + bf_lo(q1.x)) + (bf_lo(q2.x) + bf_lo(q3.x)))
        + ((bf_lo(q4.x) + bf_lo(q5.x)) + (bf_lo(q6.x) + bf_lo(q7.x)));
    a1 += ((bf_hi(q0.x) + bf_hi(q1.x)) + (bf_hi(q2.x) + bf_hi(q3.x)))
        + ((bf_hi(q4.x) + bf_hi(q5.x)) + (bf_hi(q6.x) + bf_hi(q7.x)));
    a2 += ((bf_lo(q0.y) + bf_lo(q1.y)) + (bf_lo(q2.y) + bf_lo(q3.y)))
        + ((bf_lo(q4.y) + bf_lo(q5.y)) + (bf_lo(q6.y) + bf_lo(q7.y)));
    a3 += ((bf_hi(q0.y) + bf_hi(q1.y)) + (bf_hi(q2.y) + bf_hi(q3.y)))
        + ((bf_hi(q4.y) + bf_hi(q5.y)) + (bf_hi(q6.y) + bf_hi(q7.y)));
  }
  float dv = dinv[v];
  float4 bg = *(const float4*)(b_gcn + ln * 4);
  a0 = fmaxf(fmaf(dv, a0, bg.x), 0.f);
  a1 = fmaxf(fmaf(dv, a1, bg.y), 0.f);
  a2 = fmaxf(fmaf(dv, a2, bg.z), 0.f);
  a3 = fmaxf(fmaf(dv, a3, bg.w), 0.f);
  uint2 o; o.x = fpack2(a0, a1); o.y = fpack2(a2, a3);
  *(uint2*)(h_b + (size_t)v * 64 + ln * 2) = o;
}

// ---------- phase 2: 2 nodes per wave; aggx gather + ea gather ----------
__global__ __launch_bounds__(256) void k_phase2(const u32* h_b, const int* row_ptr, const int2* ce,
                                                const float* edge_attr, const float* degf,
                                                u16* A2b, int n){
  int lane = threadIdx.x & 63;
  int ln = lane & 31;
  int half = lane >> 5;
  int v = blockIdx.x * 8 + ((threadIdx.x >> 6) << 1) + half;
  if (v >= n) return;
  uint2 sp = *(const uint2*)(h_b + (size_t)v * 64 + ln * 2);
  float a0 = bf_lo(sp.x), a1 = bf_hi(sp.x), a2 = bf_lo(sp.y), a3 = bf_hi(sp.y);
  float es = 0.f;                  // channel ln&15, slot-group ln>>4 (4 edges each)
  int ch = ln & 15, grp = ln >> 4;
  int e0 = row_ptr[v], e1 = row_ptr[v + 1];
  for (int i = e0; i < e1; i += 8){
    const int4* cp = (const int4*)(ce + i);
    int4 A = cp[0], B = cp[1], C = cp[2], D = cp[3];
    int gb = i + grp * 4;
    int2 c0 = ce[gb + 0];
    int2 c1 = ce[gb + 1];
    int2 c2 = ce[gb + 2];
    int2 c3 = ce[gb + 3];
    uint2 q0 = *(const uint2*)(h_b + (size_t)A.x * 64 + ln * 2);
    uint2 q1 = *(const uint2*)(h_b + (size_t)A.z * 64 + ln * 2);
    uint2 q2 = *(const uint2*)(h_b + (size_t)B.x * 64 + ln * 2);
    uint2 q3 = *(const uint2*)(h_b + (size_t)B.z * 64 + ln * 2);
    uint2 q4 = *(const uint2*)(h_b + (size_t)C.x * 64 + ln * 2);
    uint2 q5 = *(const uint2*)(h_b + (size_t)C.z * 64 + ln * 2);
    uint2 q6 = *(const uint2*)(h_b + (size_t)D.x * 64 + ln * 2);
    uint2 q7 = *(const uint2*)(h_b + (size_t)D.z * 64 + ln * 2);
    float m0 = (c0.x != n) ? 1.f : 0.f;
    float m1 = (c1.x != n) ? 1.f : 0.f;
    float m2 = (c2.x != n) ? 1.f : 0.f;
    float m3 = (c3.x != n) ? 1.f : 0.f;
    float v0 = edge_attr[(size_t)(c0.y >> 1) * DE + ch];
    float v1 = edge_attr[(size_t)(c1.y >> 1) * DE + ch];
    float v2 = edge_attr[(size_t)(c2.y >> 1) * DE + ch];
    float v3 = edge_attr[(size_t)(c3.y >> 1) * DE + ch];
    es = fmaf(m0, v0, es);
    es = fmaf(m1, v1, es);
    es = fmaf(m2, v2, es);
    es = fmaf(m3, v3, es);
    a0 += ((bf_lo(q0.x) + bf_lo(q1.x)) + (bf_lo(q2.x) + bf_lo(q3.x)))
        + ((bf_lo(q4.x) + bf_lo(q5.x)) + (bf_lo(q6.x) + bf_lo(q7.x)));
    a1 += ((bf_hi(q0.x) + bf_hi(q1.x)) + (bf_hi(q2.x) + bf_hi(q3.x)))
        + ((bf_hi(q4.x) + bf_hi(q5.x)) + (bf_hi(q6.x) + bf_hi(q7.x)));
    a2 += ((bf_lo(q0.y) + bf_lo(q1.y)) + (bf_lo(q2.y) + bf_lo(q3.y)))
        + ((bf_lo(q4.y) + bf_lo(q5.y)) + (bf_lo(q6.y) + bf_lo(q7.y)));
    a3 += ((bf_hi(q0.y) + bf_hi(q1.y)) + (bf_hi(q2.y) + bf_hi(q3.y)))
        + ((bf_hi(q4.y) + bf_hi(q5.y)) + (bf_hi(q6.y) + bf_hi(q7.y)));
  }
  // within-half reduction over the 2 slot groups, then wave-uniform pair pick
  es += __shfl_xor(es, 16);
  float c0v = __shfl(es, half * 32 + (ln & 7) * 2);
  float c1v = __shfl(es, half * 32 + (ln & 7) * 2 + 1);
  u32* rowp = (u32*)(A2b + (size_t)v * 160);
  uint2 o; o.x = fpack2(a0, a1); o.y = fpack2(a2, a3);
  *(uint2*)(rowp + ln * 2) = o;
  if (ln < 8){
    rowp[64 + ln] = fpack2(c0v + 1.0f, c1v + 1.0f);
  } else if (ln < 16){
    rowp[64 + ln] = (ln == 8) ? (u32)f2bf(degf[v]) : 0u;
  }
}

// ---------- pooling ----------
__global__ void k_starts(const int* batch, int* start, int n, int g){
  int v = blockIdx.x * blockDim.x + threadIdx.x;
  if (v >= n) return;
  int b = batch[v];
  int prev = (v == 0) ? -1 : batch[v - 1];
  for (int q = prev + 1; q <= b; ++q) start[q] = v;
  if (v == n - 1){ for (int q = b + 1; q <= g; ++q) start[q] = n; }
}
// stage A: (graph, sub) blocks; 32 sub-blocks per graph for occupancy
__global__ __launch_bounds__(256) void k_pool_a(const u32* h2_b, const int* start, float* partialp){
  __shared__ float2 red[256];
  int g = blockIdx.x >> 5;
  int s = blockIdx.x & (PSUB - 1);
  int s0 = start[g], s1 = start[g + 1];
  int tid = threadIdx.x;
  int cu = tid & 63, rr = tid >> 6;
  float ax = 0.f, ay = 0.f;
  for (int r = s0 + s * 4 + rr; r < s1; r += PSUB * 4){
    u32 q = h2_b[(size_t)r * 64 + cu];
    ax += bf_lo(q); ay += bf_hi(q);
  }
  red[tid] = make_float2(ax, ay);
  __syncthreads();
  if (rr == 0){
    #pragma unroll
    for (int p = 1; p < 4; p++){ float2 o = red[cu + (p << 6)]; ax += o.x; ay += o.y; }
    *(float2*)(partialp + (size_t)blockIdx.x * 128 + cu * 2) = make_float2(ax, ay);
  }
}
// stage B fused with final linear: reduce 32 partials, mean, @ W_out + b_out
__global__ __launch_bounds__(128) void k_poolb_final(const float* partialp, const int* start,
                                                     const float* W_out, const float* b_out,
                                                     float* out){
  __shared__ float pl[DH];
  int g = blockIdx.x, c = threadIdx.x;
  float sum = 0.f;
  #pragma unroll 4
  for (int s = 0; s < PSUB; ++s) sum += partialp[((size_t)g * PSUB + s) * 128 + c];
  int cntg = start[g + 1] - start[g]; if (cntg < 1) cntg = 1;
  pl[c] = sum / (float)cntg;
  __syncthreads();
  float acc = b_out[c];
  for (int k = 0; k < DH; ++k) acc += pl[k] * W_out[k * DO + c];
  out[g * DO + c] = acc;
}

extern "C" void kernel_launch(void* const* d_in, const int* in_sizes, int n_in,
                              void* d_out, int out_size, void* d_ws, size_t ws_size,
                              hipStream_t stream){
  const float* x         = (const float*)d_in[0];
  const int*   edge_index= (const int*)  d_in[1];
  const float* edge_attr = (const float*)d_in[2];
  const int*   batch     = (const int*)  d_in[3];
  const float* W_gcn     = (const float*)d_in[4];
  const float* b_gcn     = (const float*)d_in[5];
  const float* W_le      = (const float*)d_in[6];
  const float* b_le      = (const float*)d_in[7];
  const float* W_lin     = (const float*)d_in[8];
  const float* b_lin     = (const float*)d_in[9];
  const float* W_out     = (const float*)d_in[10];
  const float* b_out     = (const float*)d_in[11];
  float* out = (float*)d_out;

  const int n  = in_sizes[0] / DV;       // 100000
  const int e2 = in_sizes[1] / 2;        // 1600000 directed edges
  const int g  = out_size / DO;          // 64
  const int* srcp = edge_index;
  const int* dstp = edge_index + e2;
  const int e2pad = e2 + 7 * n + 8;      // CSR capacity with per-row pad-to-8

  char* ws = (char*)d_ws;
  size_t off = 0;
  auto alloc = [&](size_t bytes) -> char* {
    char* p = ws + off; off = (off + bytes + 255) & ~(size_t)255; return p;
  };

  int*   cnt     = (int*)  alloc((size_t)n * 4);
  int*   row_ptr = (int*)  alloc((size_t)(n + 1) * 4);
  int*   rank    = (int*)  alloc((size_t)e2 * 4);
  int*   partial = (int*)  alloc((size_t)n * 4);
  int*   bsums   = (int*)  alloc(512);
  int*   bexc    = (int*)  alloc(512);
  float* dinv    = (float*)alloc((size_t)n * 4);
  float* degf    = (float*)alloc((size_t)n * 4);
  int*   startg  = (int*)  alloc((size_t)(g + 1) * 4);
  float* partialp= (float*)alloc((size_t)g * PSUB * 128 * 4);
  float* Wfull   = (float*)alloc(160 * DH * 4);
  u32*   h_b     = (u32*)  alloc((size_t)(n + 1) * 64 * 4);  // +1 zero row
  int2*  ce      = (int2*) alloc((size_t)e2pad * 8);
  u32*   h2_b    = (u32*)  alloc((size_t)n * 64 * 4);
  // region A: xws (bf16, [N+1,128]) later overwritten by A2 (bf16, [N,160])
  size_t szXW = (size_t)(n + 1) * 64 * 4, szA2 = (size_t)n * 160 * 2;
  char* regionA = alloc(szA2 > szXW ? szA2 : szXW);
  u32* xws_b = (u32*)regionA;
  u16* A2b   = (u16*)regionA;

  const int nb1024 = (n + 1023) / 1024;  // must be <= 128 for k_scan2

  k_init   <<<(n + 255) / 256, 256, 0, stream>>>(cnt, n);
  k_count  <<<(e2 + 255) / 256, 256, 0, stream>>>(dstp, cnt, rank, e2);
  k_scan1  <<<nb1024, 256, 0, stream>>>(cnt, partial, bsums, n);
  k_scan2  <<<1, 128, 0, stream>>>(bsums, bexc, nb1024);
  k_scan3  <<<(n + 255) / 256, 256, 0, stream>>>(partial, bexc, row_ptr, n);
  k_prep   <<<(n + 255) / 256, 256, 0, stream>>>(cnt, dinv, degf, n);
  k_scatter<<<(e2 + 255) / 256, 256, 0, stream>>>(srcp, dstp, rank, row_ptr, ce, e2);
  k_pad    <<<(n + 255) / 256, 256, 0, stream>>>(row_ptr, cnt, ce,
                                                 xws_b + (size_t)n * 64, h_b + (size_t)n * 64, n);
  k_wcombo <<<1, 128, 0, stream>>>(W_lin, b_lin, W_le, b_le, Wfull);

  k_gemm_mfma<DV, false, false, true><<<(n + 63) / 64, 256, 0, stream>>>(x, W_gcn, xws_b, dinv, n);
  k_phase1 <<<(n + 7) / 8, 256, 0, stream>>>(xws_b, row_ptr, ce, dinv, b_gcn, h_b, n);
  k_phase2 <<<(n + 7) / 8, 256, 0, stream>>>(h_b, row_ptr, ce, edge_attr, degf, A2b, n);
  k_gemm_mfma<160, true, true, false><<<(n + 63) / 64, 256, 0, stream>>>(A2b, Wfull, h2_b, (const float*)nullptr, n);

  k_starts      <<<(n + 255) / 256, 256, 0, stream>>>(batch, startg, n, g);
  k_pool_a      <<<g * PSUB, 256, 0, stream>>>(h2_b, startg, partialp);
  k_poolb_final <<<g, 128, 0, stream>>>(partialp, startg, W_out, b_out, out);
}

// Round 8
// 480.233 us; speedup vs baseline: 2.0707x; 1.1055x over previous
//
#include <hip/hip_runtime.h>
#include <hip/hip_bf16.h>
#include <cstddef>

typedef unsigned int  u32;
typedef unsigned short u16;
typedef __attribute__((ext_vector_type(8))) short short8;
typedef __attribute__((ext_vector_type(4))) float f32x4;
typedef __attribute__((ext_vector_type(2))) float f32x2;

#define DV 128
#define DH 128
#define DE 16
#define DO 128
#define PSUB 32   // pooling sub-blocks per graph

// ---------- bf16 helpers (bit tricks, RNE) ----------
__device__ inline float bf_lo(u32 u){ return __uint_as_float(u << 16); }
__device__ inline float bf_hi(u32 u){ return __uint_as_float(u & 0xFFFF0000u); }
__device__ inline u32 fpack2(float a, float b){
  u32 ua = __float_as_uint(a), ub = __float_as_uint(b);
  ua += 0x7FFFu + ((ua >> 16) & 1u);
  ub += 0x7FFFu + ((ub >> 16) & 1u);
  return (ua >> 16) | (ub & 0xFFFF0000u);
}
__device__ inline u16 f2bf(float a){
  u32 ua = __float_as_uint(a); ua += 0x7FFFu + ((ua >> 16) & 1u); return (u16)(ua >> 16);
}

// ---------- fp8 (OCP e4m3) helpers: 4 channels per u32 ----------
__device__ inline void acc_fp8(u32 s, float& a0, float& a1, float& a2, float& a3){
  f32x2 lo = __builtin_amdgcn_cvt_pk_f32_fp8((int)s, false);
  f32x2 hi = __builtin_amdgcn_cvt_pk_f32_fp8((int)s, true);
  a0 += lo.x; a1 += lo.y; a2 += hi.x; a3 += hi.y;
}
__device__ inline u32 pack_fp8(float a0, float a1, float a2, float a3){
  int o = __builtin_amdgcn_cvt_pk_fp8_f32(a0, a1, 0, false);
  o = __builtin_amdgcn_cvt_pk_fp8_f32(a2, a3, o, true);
  return (u32)o;
}

// ---------- CSR build ----------
__global__ void k_init(int* cnt, int n){
  int v = blockIdx.x * blockDim.x + threadIdx.x;
  if (v < n) cnt[v] = 0;
}
// count AND record each edge's rank within its dst bucket (coalesced store)
__global__ void k_count(const int* dst, int* cnt, int* rank, int e2){
  int j = blockIdx.x * blockDim.x + threadIdx.x;
  if (j < e2) rank[j] = atomicAdd(&cnt[dst[j]], 1);
}
// scan of PADDED counts: pc = (cnt+7)&~7  (rows padded to multiple of 8)
__global__ __launch_bounds__(256) void k_scan1(const int* cnt, int* partial, int* bsums, int n){
  __shared__ int lds[256];
  int t = threadIdx.x;
  int base = blockIdx.x * 1024 + t * 4;
  int v0=0,v1=0,v2=0,v3=0;
  if (base + 3 < n){ int4 q = *(const int4*)(cnt + base); v0=q.x; v1=q.y; v2=q.z; v3=q.w; }
  else {
    if (base + 0 < n) v0 = cnt[base];
    if (base + 1 < n) v1 = cnt[base+1];
    if (base + 2 < n) v2 = cnt[base+2];
  }
  v0 = (v0 + 7) & ~7; v1 = (v1 + 7) & ~7; v2 = (v2 + 7) & ~7; v3 = (v3 + 7) & ~7;
  v1 += v0; v2 += v1; v3 += v2;
  lds[t] = v3; __syncthreads();
  for (int off = 1; off < 256; off <<= 1){
    int x = (t >= off) ? lds[t - off] : 0;
    __syncthreads();
    lds[t] += x;
    __syncthreads();
  }
  int add = (t > 0) ? lds[t - 1] : 0;
  if (base + 3 < n){
    int4 q; q.x = v0+add; q.y = v1+add; q.z = v2+add; q.w = v3+add;
    *(int4*)(partial + base) = q;
  } else {
    if (base + 0 < n) partial[base]   = v0 + add;
    if (base + 1 < n) partial[base+1] = v1 + add;
    if (base + 2 < n) partial[base+2] = v2 + add;
  }
  if (t == 255) bsums[blockIdx.x] = lds[255];
}
__global__ void k_scan2(const int* bsums, int* bexc, int nb){
  __shared__ int lds[128];
  int t = threadIdx.x;
  lds[t] = (t < nb) ? bsums[t] : 0;
  __syncthreads();
  for (int off = 1; off < 128; off <<= 1){
    int x = (t >= off) ? lds[t - off] : 0;
    __syncthreads();
    lds[t] += x;
    __syncthreads();
  }
  if (t < nb) bexc[t] = (t > 0) ? lds[t - 1] : 0;
}
__global__ void k_scan3(const int* partial, const int* bexc, int* row_ptr, int n){
  int i = blockIdx.x * blockDim.x + threadIdx.x;
  if (i < n) row_ptr[i + 1] = partial[i] + bexc[i >> 10];
  if (i == 0) row_ptr[0] = 0;
}
__global__ void k_prep(const int* cnt, float* dinv, float* degf, int n){
  int v = blockIdx.x * blockDim.x + threadIdx.x;
  if (v < n){
    float c = (float)(cnt[v] + 1);   // in-degree + self-loop
    dinv[v] = rsqrtf(c);
    degf[v] = c;
  }
}
// scatter WITHOUT atomic: pos = row_ptr[dst] + precomputed rank
__global__ void k_scatter(const int* src, const int* dst, const int* rank,
                          const int* row_ptr, int2* ce, int e2){
  int j = blockIdx.x * blockDim.x + threadIdx.x;
  if (j < e2){
    int d = dst[j];
    int pos = row_ptr[d] + rank[j];
    ce[pos] = make_int2(src[j], j);
  }
}
// fill CSR pad slots with {n, 0}; zero the fp8 gather tables' row n (32 u32 each)
__global__ void k_pad(const int* row_ptr, const int* cnt, int2* ce,
                      u32* xws_zrow, u32* h_zrow, int n){
  int v = blockIdx.x * blockDim.x + threadIdx.x;
  if (v < n){
    int s = row_ptr[v] + cnt[v], e = row_ptr[v + 1];
    for (int i = s; i < e; ++i) ce[i] = make_int2(n, 0);
  }
  if (blockIdx.x == 0 && threadIdx.x < 32){
    xws_zrow[threadIdx.x] = 0u;
    h_zrow[threadIdx.x] = 0u;
  }
}

// ---------- fold W_le@W_bot and biases into the h2 GEMM weight ----------
__global__ __launch_bounds__(128) void k_wcombo(const float* W_lin, const float* b_lin,
                                                const float* W_le, const float* b_le, float* Wfull){
  __shared__ float wle[DE * DH];
  int c = threadIdx.x;
  for (int i = c; i < DE * DH; i += 128) wle[i] = W_le[i];
  __syncthreads();
  float combo[DE];
  #pragma unroll
  for (int i = 0; i < DE; i++) combo[i] = 0.f;
  float bacc = b_lin[c];
  for (int k = 0; k < DH; ++k){
    float wv = W_lin[(size_t)(DH + k) * DH + c];   // W_bot[k][c]
    bacc += b_le[k] * wv;
    #pragma unroll
    for (int i = 0; i < DE; i++) combo[i] += wle[i * DH + k] * wv;
  }
  for (int r = 0; r < DH; ++r) Wfull[r * DH + c] = W_lin[r * DH + c];
  #pragma unroll
  for (int i = 0; i < DE; i++) Wfull[(DH + i) * DH + c] = combo[i];
  Wfull[144 * DH + c] = bacc;
  for (int r = 145; r < 160; ++r) Wfull[r * DH + c] = 0.f;
}

// ---------- MFMA GEMM: [M,K] @ [K,128] -> bf16 (stride 64 u32) or fp8 (stride 32 u32) ----------
template<int K, bool RELU, bool ABF16, bool SCALE, bool OFP8>
__global__ __launch_bounds__(256) void k_gemm_mfma(const void* Ap, const float* W, u32* outb,
                                                   const float* scale, int M){
  constexpr int SA = K + 8;      // u16 stride
  constexpr int CS = 136;        // Ct stride (u16)
  __shared__ u16 Wt[128 * SA];   // W transposed, bf16: Wt[c][k]
  __shared__ u16 At[64 * SA];    // A tile bf16 (reused as Ct in epilogue)
  int tid = threadIdx.x;
  int row0 = blockIdx.x * 64;

  // ---- stage Wt: coalesced fp32 reads, transposed bf16x8 LDS writes ----
  {
    int c = tid & 127, half = tid >> 7;
    for (int g = half; g < K / 8; g += 2){
      int k0 = g * 8;
      float w0 = W[(size_t)(k0+0)*128 + c], w1 = W[(size_t)(k0+1)*128 + c];
      float w2 = W[(size_t)(k0+2)*128 + c], w3 = W[(size_t)(k0+3)*128 + c];
      float w4 = W[(size_t)(k0+4)*128 + c], w5 = W[(size_t)(k0+5)*128 + c];
      float w6 = W[(size_t)(k0+6)*128 + c], w7 = W[(size_t)(k0+7)*128 + c];
      uint4 pk;
      pk.x = fpack2(w0, w1); pk.y = fpack2(w2, w3);
      pk.z = fpack2(w4, w5); pk.w = fpack2(w6, w7);
      *(uint4*)&Wt[c * SA + k0] = pk;
    }
  }
  // ---- stage At ----
  constexpr int CH = K / 8;
  for (int idx = tid; idx < 64 * CH; idx += 256){
    int r = idx / CH, ch = idx - r * CH;
    int gr = row0 + r; if (gr > M - 1) gr = M - 1;
    uint4 pk;
    if (ABF16){
      pk = *(const uint4*)((const u16*)Ap + (size_t)gr * K + ch * 8);
    } else {
      const float* A = (const float*)Ap + (size_t)gr * K + ch * 8;
      float4 q0 = *(const float4*)A;
      float4 q1 = *(const float4*)(A + 4);
      pk.x = fpack2(q0.x, q0.y); pk.y = fpack2(q0.z, q0.w);
      pk.z = fpack2(q1.x, q1.y); pk.w = fpack2(q1.z, q1.w);
    }
    *(uint4*)&At[r * SA + ch * 8] = pk;
  }
  __syncthreads();

  // ---- MFMA main loop ----
  int l = tid & 63, w = tid >> 6;
  int m = l & 15, quad = l >> 4;
  f32x4 acc[8];
  #pragma unroll
  for (int ct = 0; ct < 8; ++ct) acc[ct] = (f32x4){0.f, 0.f, 0.f, 0.f};
  #pragma unroll
  for (int ks = 0; ks < K; ks += 32){
    short8 av = *(const short8*)&At[(w * 16 + m) * SA + ks + quad * 8];
    #pragma unroll
    for (int ct = 0; ct < 8; ++ct){
      short8 bv = *(const short8*)&Wt[(ct * 16 + m) * SA + ks + quad * 8];
      acc[ct] = __builtin_amdgcn_mfma_f32_16x16x32_bf16(av, bv, acc[ct], 0, 0, 0);
    }
  }
  __syncthreads();   // done reading At — reuse as Ct

  // ---- epilogue: scale/relu, bf16 pack into Ct ----
  u16* Ct = At;
  float sc[4];
  if (SCALE){
    #pragma unroll
    for (int r = 0; r < 4; ++r){
      int gr = row0 + w * 16 + quad * 4 + r;
      sc[r] = scale[gr < M ? gr : (M - 1)];
    }
  }
  #pragma unroll
  for (int ct = 0; ct < 8; ++ct){
    #pragma unroll
    for (int r = 0; r < 4; ++r){
      float vv = acc[ct][r];
      if (SCALE) vv *= sc[r];
      if (RELU)  vv = fmaxf(vv, 0.f);
      Ct[(w * 16 + quad * 4 + r) * CS + ct * 16 + m] = f2bf(vv);
    }
  }
  __syncthreads();
  if (OFP8){
    // convert bf16 Ct -> fp8 rows (128 B), coalesced uint2 stores
    for (int idx = tid; idx < 64 * 16; idx += 256){
      int r = idx >> 4, c8 = idx & 15;
      int gr = row0 + r;
      if (gr < M){
        uint4 qv = *(const uint4*)&Ct[r * CS + c8 * 8];
        uint2 ov;
        ov.x = (u32)__builtin_amdgcn_cvt_pk_fp8_f32(bf_lo(qv.y), bf_hi(qv.y),
               __builtin_amdgcn_cvt_pk_fp8_f32(bf_lo(qv.x), bf_hi(qv.x), 0, false), true);
        ov.y = (u32)__builtin_amdgcn_cvt_pk_fp8_f32(bf_lo(qv.w), bf_hi(qv.w),
               __builtin_amdgcn_cvt_pk_fp8_f32(bf_lo(qv.z), bf_hi(qv.z), 0, false), true);
        *(uint2*)(outb + (size_t)gr * 32 + c8 * 2) = ov;
      }
    }
  } else {
    for (int idx = tid; idx < 64 * 16; idx += 256){
      int r = idx >> 4, ch = idx & 15;
      int gr = row0 + r;
      if (gr < M){
        uint4 q = *(const uint4*)&Ct[r * CS + ch * 8];
        *(uint4*)(outb + (size_t)gr * 64 + ch * 4) = q;
      }
    }
  }
}

// ---------- phase 1: fp8 table, 2 nodes/wave, software-pipelined 16-deep gathers ----------
__global__ __launch_bounds__(256) void k_phase1(const u32* xws8, const int* row_ptr, const int2* ce,
                                                const float* dinv, const float* b_gcn, u32* h8, int n){
  int lane = threadIdx.x & 63;
  int ln = lane & 31;
  int v = blockIdx.x * 8 + ((threadIdx.x >> 6) << 1) + (lane >> 5);
  if (v >= n) return;
  u32 sp = xws8[(size_t)v * 32 + ln];
  float a0 = 0.f, a1 = 0.f, a2 = 0.f, a3 = 0.f;
  acc_fp8(sp, a0, a1, a2, a3);
  int e0 = row_ptr[v], e1 = row_ptr[v + 1];
  int i = e0;
  u32 q0=0,q1=0,q2=0,q3=0,q4=0,q5=0,q6=0,q7=0;
  if (i < e1){
    const int4* cp = (const int4*)(ce + i);
    int4 A = cp[0], B = cp[1], C = cp[2], D = cp[3];
    q0 = xws8[(size_t)A.x * 32 + ln]; q1 = xws8[(size_t)A.z * 32 + ln];
    q2 = xws8[(size_t)B.x * 32 + ln]; q3 = xws8[(size_t)B.z * 32 + ln];
    q4 = xws8[(size_t)C.x * 32 + ln]; q5 = xws8[(size_t)C.z * 32 + ln];
    q6 = xws8[(size_t)D.x * 32 + ln]; q7 = xws8[(size_t)D.z * 32 + ln];
  }
  for (; i + 8 < e1; i += 8){
    const int4* cp2 = (const int4*)(ce + i + 8);
    int4 A = cp2[0], B = cp2[1], C = cp2[2], D = cp2[3];
    u32 p0 = xws8[(size_t)A.x * 32 + ln], p1 = xws8[(size_t)A.z * 32 + ln];
    u32 p2 = xws8[(size_t)B.x * 32 + ln], p3 = xws8[(size_t)B.z * 32 + ln];
    u32 p4 = xws8[(size_t)C.x * 32 + ln], p5 = xws8[(size_t)C.z * 32 + ln];
    u32 p6 = xws8[(size_t)D.x * 32 + ln], p7 = xws8[(size_t)D.z * 32 + ln];
    acc_fp8(q0, a0, a1, a2, a3); acc_fp8(q1, a0, a1, a2, a3);
    acc_fp8(q2, a0, a1, a2, a3); acc_fp8(q3, a0, a1, a2, a3);
    acc_fp8(q4, a0, a1, a2, a3); acc_fp8(q5, a0, a1, a2, a3);
    acc_fp8(q6, a0, a1, a2, a3); acc_fp8(q7, a0, a1, a2, a3);
    q0=p0; q1=p1; q2=p2; q3=p3; q4=p4; q5=p5; q6=p6; q7=p7;
  }
  if (i < e1){
    acc_fp8(q0, a0, a1, a2, a3); acc_fp8(q1, a0, a1, a2, a3);
    acc_fp8(q2, a0, a1, a2, a3); acc_fp8(q3, a0, a1, a2, a3);
    acc_fp8(q4, a0, a1, a2, a3); acc_fp8(q5, a0, a1, a2, a3);
    acc_fp8(q6, a0, a1, a2, a3); acc_fp8(q7, a0, a1, a2, a3);
  }
  float dv = dinv[v];
  float4 bg = *(const float4*)(b_gcn + ln * 4);
  a0 = fmaxf(fmaf(dv, a0, bg.x), 0.f);
  a1 = fmaxf(fmaf(dv, a1, bg.y), 0.f);
  a2 = fmaxf(fmaf(dv, a2, bg.z), 0.f);
  a3 = fmaxf(fmaf(dv, a3, bg.w), 0.f);
  h8[(size_t)v * 32 + ln] = pack_fp8(a0, a1, a2, a3);
}

// ---------- phase 2: fp8 h-table, pipelined; ea gather via cndmask-selected slots ----------
__global__ __launch_bounds__(256) void k_phase2(const u32* h8, const int* row_ptr, const int2* ce,
                                                const float* edge_attr, const float* degf,
                                                u16* A2b, int n){
  int lane = threadIdx.x & 63;
  int ln = lane & 31;
  int half = lane >> 5;
  int v = blockIdx.x * 8 + ((threadIdx.x >> 6) << 1) + half;
  if (v >= n) return;
  u32 sp = h8[(size_t)v * 32 + ln];
  float a0 = 0.f, a1 = 0.f, a2 = 0.f, a3 = 0.f;
  acc_fp8(sp, a0, a1, a2, a3);
  float es = 0.f;                  // channel ln&15, slot-group ln>>4 (4 edges each)
  int ch = ln & 15, grp = ln >> 4;
  int e0 = row_ptr[v], e1 = row_ptr[v + 1];
  int i = e0;
  u32 q0=0,q1=0,q2=0,q3=0,q4=0,q5=0,q6=0,q7=0;
  int4 A = {0,0,0,0}, B = {0,0,0,0}, C = {0,0,0,0}, D = {0,0,0,0};
  if (i < e1){
    const int4* cp = (const int4*)(ce + i);
    A = cp[0]; B = cp[1]; C = cp[2]; D = cp[3];
    q0 = h8[(size_t)A.x * 32 + ln]; q1 = h8[(size_t)A.z * 32 + ln];
    q2 = h8[(size_t)B.x * 32 + ln]; q3 = h8[(size_t)B.z * 32 + ln];
    q4 = h8[(size_t)C.x * 32 + ln]; q5 = h8[(size_t)C.z * 32 + ln];
    q6 = h8[(size_t)D.x * 32 + ln]; q7 = h8[(size_t)D.z * 32 + ln];
  }
  for (; i + 8 < e1; i += 8){
    const int4* cp2 = (const int4*)(ce + i + 8);
    int4 A2 = cp2[0], B2 = cp2[1], C2 = cp2[2], D2 = cp2[3];
    // ea slots for CURRENT block from regs (grp 0 -> A,B; grp 1 -> C,D)
    int s0x = grp ? C.x : A.x, s0y = grp ? C.y : A.y;
    int s1x = grp ? C.z : A.z, s1y = grp ? C.w : A.w;
    int s2x = grp ? D.x : B.x, s2y = grp ? D.y : B.y;
    int s3x = grp ? D.z : B.z, s3y = grp ? D.w : B.w;
    float v0 = edge_attr[(size_t)(s0y >> 1) * DE + ch];
    float v1 = edge_attr[(size_t)(s1y >> 1) * DE + ch];
    float v2 = edge_attr[(size_t)(s2y >> 1) * DE + ch];
    float v3 = edge_attr[(size_t)(s3y >> 1) * DE + ch];
    // next block's gathers
    u32 p0 = h8[(size_t)A2.x * 32 + ln], p1 = h8[(size_t)A2.z * 32 + ln];
    u32 p2 = h8[(size_t)B2.x * 32 + ln], p3 = h8[(size_t)B2.z * 32 + ln];
    u32 p4 = h8[(size_t)C2.x * 32 + ln], p5 = h8[(size_t)C2.z * 32 + ln];
    u32 p6 = h8[(size_t)D2.x * 32 + ln], p7 = h8[(size_t)D2.z * 32 + ln];
    // consume current
    acc_fp8(q0, a0, a1, a2, a3); acc_fp8(q1, a0, a1, a2, a3);
    acc_fp8(q2, a0, a1, a2, a3); acc_fp8(q3, a0, a1, a2, a3);
    acc_fp8(q4, a0, a1, a2, a3); acc_fp8(q5, a0, a1, a2, a3);
    acc_fp8(q6, a0, a1, a2, a3); acc_fp8(q7, a0, a1, a2, a3);
    es = fmaf((s0x != n) ? 1.f : 0.f, v0, es);
    es = fmaf((s1x != n) ? 1.f : 0.f, v1, es);
    es = fmaf((s2x != n) ? 1.f : 0.f, v2, es);
    es = fmaf((s3x != n) ? 1.f : 0.f, v3, es);
    q0=p0; q1=p1; q2=p2; q3=p3; q4=p4; q5=p5; q6=p6; q7=p7;
    A=A2; B=B2; C=C2; D=D2;
  }
  if (i < e1){
    int s0x = grp ? C.x : A.x, s0y = grp ? C.y : A.y;
    int s1x = grp ? C.z : A.z, s1y = grp ? C.w : A.w;
    int s2x = grp ? D.x : B.x, s2y = grp ? D.y : B.y;
    int s3x = grp ? D.z : B.z, s3y = grp ? D.w : B.w;
    float v0 = edge_attr[(size_t)(s0y >> 1) * DE + ch];
    float v1 = edge_attr[(size_t)(s1y >> 1) * DE + ch];
    float v2 = edge_attr[(size_t)(s2y >> 1) * DE + ch];
    float v3 = edge_attr[(size_t)(s3y >> 1) * DE + ch];
    acc_fp8(q0, a0, a1, a2, a3); acc_fp8(q1, a0, a1, a2, a3);
    acc_fp8(q2, a0, a1, a2, a3); acc_fp8(q3, a0, a1, a2, a3);
    acc_fp8(q4, a0, a1, a2, a3); acc_fp8(q5, a0, a1, a2, a3);
    acc_fp8(q6, a0, a1, a2, a3); acc_fp8(q7, a0, a1, a2, a3);
    es = fmaf((s0x != n) ? 1.f : 0.f, v0, es);
    es = fmaf((s1x != n) ? 1.f : 0.f, v1, es);
    es = fmaf((s2x != n) ? 1.f : 0.f, v2, es);
    es = fmaf((s3x != n) ? 1.f : 0.f, v3, es);
  }
  // within-half reduction over the 2 slot groups, then wave-uniform pair pick
  es += __shfl_xor(es, 16);
  float c0v = __shfl(es, half * 32 + (ln & 7) * 2);
  float c1v = __shfl(es, half * 32 + (ln & 7) * 2 + 1);
  u32* rowp = (u32*)(A2b + (size_t)v * 160);
  uint2 o; o.x = fpack2(a0, a1); o.y = fpack2(a2, a3);
  *(uint2*)(rowp + ln * 2) = o;
  if (ln < 8){
    rowp[64 + ln] = fpack2(c0v + 1.0f, c1v + 1.0f);
  } else if (ln < 16){
    rowp[64 + ln] = (ln == 8) ? (u32)f2bf(degf[v]) : 0u;
  }
}

// ---------- pooling ----------
__global__ void k_starts(const int* batch, int* start, int n, int g){
  int v = blockIdx.x * blockDim.x + threadIdx.x;
  if (v >= n) return;
  int b = batch[v];
  int prev = (v == 0) ? -1 : batch[v - 1];
  for (int q = prev + 1; q <= b; ++q) start[q] = v;
  if (v == n - 1){ for (int q = b + 1; q <= g; ++q) start[q] = n; }
}
// stage A: (graph, sub) blocks; 32 sub-blocks per graph for occupancy
__global__ __launch_bounds__(256) void k_pool_a(const u32* h2_b, const int* start, float* partialp){
  __shared__ float2 red[256];
  int g = blockIdx.x >> 5;
  int s = blockIdx.x & (PSUB - 1);
  int s0 = start[g], s1 = start[g + 1];
  int tid = threadIdx.x;
  int cu = tid & 63, rr = tid >> 6;
  float ax = 0.f, ay = 0.f;
  for (int r = s0 + s * 4 + rr; r < s1; r += PSUB * 4){
    u32 q = h2_b[(size_t)r * 64 + cu];
    ax += bf_lo(q); ay += bf_hi(q);
  }
  red[tid] = make_float2(ax, ay);
  __syncthreads();
  if (rr == 0){
    #pragma unroll
    for (int p = 1; p < 4; p++){ float2 o = red[cu + (p << 6)]; ax += o.x; ay += o.y; }
    *(float2*)(partialp + (size_t)blockIdx.x * 128 + cu * 2) = make_float2(ax, ay);
  }
}
// stage B fused with final linear: reduce 32 partials, mean, @ W_out + b_out
__global__ __launch_bounds__(128) void k_poolb_final(const float* partialp, const int* start,
                                                     const float* W_out, const float* b_out,
                                                     float* out){
  __shared__ float pl[DH];
  int g = blockIdx.x, c = threadIdx.x;
  float sum = 0.f;
  #pragma unroll 4
  for (int s = 0; s < PSUB; ++s) sum += partialp[((size_t)g * PSUB + s) * 128 + c];
  int cntg = start[g + 1] - start[g]; if (cntg < 1) cntg = 1;
  pl[c] = sum / (float)cntg;
  __syncthreads();
  float acc = b_out[c];
  for (int k = 0; k < DH; ++k) acc += pl[k] * W_out[k * DO + c];
  out[g * DO + c] = acc;
}

extern "C" void kernel_launch(void* const* d_in, const int* in_sizes, int n_in,
                              void* d_out, int out_size, void* d_ws, size_t ws_size,
                              hipStream_t stream){
  const float* x         = (const float*)d_in[0];
  const int*   edge_index= (const int*)  d_in[1];
  const float* edge_attr = (const float*)d_in[2];
  const int*   batch     = (const int*)  d_in[3];
  const float* W_gcn     = (const float*)d_in[4];
  const float* b_gcn     = (const float*)d_in[5];
  const float* W_le      = (const float*)d_in[6];
  const float* b_le      = (const float*)d_in[7];
  const float* W_lin     = (const float*)d_in[8];
  const float* b_lin     = (const float*)d_in[9];
  const float* W_out     = (const float*)d_in[10];
  const float* b_out     = (const float*)d_in[11];
  float* out = (float*)d_out;

  const int n  = in_sizes[0] / DV;       // 100000
  const int e2 = in_sizes[1] / 2;        // 1600000 directed edges
  const int g  = out_size / DO;          // 64
  const int* srcp = edge_index;
  const int* dstp = edge_index + e2;
  const int e2pad = e2 + 7 * n + 8;      // CSR capacity with per-row pad-to-8

  char* ws = (char*)d_ws;
  size_t off = 0;
  auto alloc = [&](size_t bytes) -> char* {
    char* p = ws + off; off = (off + bytes + 255) & ~(size_t)255; return p;
  };

  int*   cnt     = (int*)  alloc((size_t)n * 4);
  int*   row_ptr = (int*)  alloc((size_t)(n + 1) * 4);
  int*   rank    = (int*)  alloc((size_t)e2 * 4);
  int*   partial = (int*)  alloc((size_t)n * 4);
  int*   bsums   = (int*)  alloc(512);
  int*   bexc    = (int*)  alloc(512);
  float* dinv    = (float*)alloc((size_t)n * 4);
  float* degf    = (float*)alloc((size_t)n * 4);
  int*   startg  = (int*)  alloc((size_t)(g + 1) * 4);
  float* partialp= (float*)alloc((size_t)g * PSUB * 128 * 4);
  float* Wfull   = (float*)alloc(160 * DH * 4);
  u32*   h8      = (u32*)  alloc((size_t)(n + 1) * 128);   // fp8 rows, +1 zero row
  int2*  ce      = (int2*) alloc((size_t)e2pad * 8);
  u32*   h2_b    = (u32*)  alloc((size_t)n * 64 * 4);
  // region A: xws8 (fp8, [N+1,128B]) later overwritten by A2 (bf16, [N,160])
  size_t szXW = (size_t)(n + 1) * 128, szA2 = (size_t)n * 160 * 2;
  char* regionA = alloc(szA2 > szXW ? szA2 : szXW);
  u32* xws8 = (u32*)regionA;
  u16* A2b  = (u16*)regionA;

  const int nb1024 = (n + 1023) / 1024;  // must be <= 128 for k_scan2

  k_init   <<<(n + 255) / 256, 256, 0, stream>>>(cnt, n);
  k_count  <<<(e2 + 255) / 256, 256, 0, stream>>>(dstp, cnt, rank, e2);
  k_scan1  <<<nb1024, 256, 0, stream>>>(cnt, partial, bsums, n);
  k_scan2  <<<1, 128, 0, stream>>>(bsums, bexc, nb1024);
  k_scan3  <<<(n + 255) / 256, 256, 0, stream>>>(partial, bexc, row_ptr, n);
  k_prep   <<<(n + 255) / 256, 256, 0, stream>>>(cnt, dinv, degf, n);
  k_scatter<<<(e2 + 255) / 256, 256, 0, stream>>>(srcp, dstp, rank, row_ptr, ce, e2);
  k_pad    <<<(n + 255) / 256, 256, 0, stream>>>(row_ptr, cnt, ce,
                                                 xws8 + (size_t)n * 32, h8 + (size_t)n * 32, n);
  k_wcombo <<<1, 128, 0, stream>>>(W_lin, b_lin, W_le, b_le, Wfull);

  k_gemm_mfma<DV, false, false, true, true><<<(n + 63) / 64, 256, 0, stream>>>(x, W_gcn, xws8, dinv, n);
  k_phase1 <<<(n + 7) / 8, 256, 0, stream>>>(xws8, row_ptr, ce, dinv, b_gcn, h8, n);
  k_phase2 <<<(n + 7) / 8, 256, 0, stream>>>(h8, row_ptr, ce, edge_attr, degf, A2b, n);
  k_gemm_mfma<160, true, true, false, false><<<(n + 63) / 64, 256, 0, stream>>>(A2b, Wfull, h2_b, (const float*)nullptr, n);

  k_starts      <<<(n + 255) / 256, 256, 0, stream>>>(batch, startg, n, g);
  k_pool_a      <<<g * PSUB, 256, 0, stream>>>(h2_b, startg, partialp);
  k_poolb_final <<<g, 128, 0, stream>>>(partialp, startg, W_out, b_out, out);
}

// Round 9
// 414.784 us; speedup vs baseline: 2.3974x; 1.1578x over previous
//
#include <hip/hip_runtime.h>
#include <hip/hip_bf16.h>
#include <cstddef>

typedef unsigned int  u32;
typedef unsigned short u16;
typedef __attribute__((ext_vector_type(8))) short short8;
typedef __attribute__((ext_vector_type(4))) float f32x4;
typedef __attribute__((ext_vector_type(2))) float f32x2;

#define DV 128
#define DH 128
#define DE 16
#define DO 128
#define PSUB 32   // pooling sub-blocks per graph

// ---------- bf16 helpers (bit tricks, RNE) ----------
__device__ inline float bf_lo(u32 u){ return __uint_as_float(u << 16); }
__device__ inline float bf_hi(u32 u){ return __uint_as_float(u & 0xFFFF0000u); }
__device__ inline u32 fpack2(float a, float b){
  u32 ua = __float_as_uint(a), ub = __float_as_uint(b);
  ua += 0x7FFFu + ((ua >> 16) & 1u);
  ub += 0x7FFFu + ((ub >> 16) & 1u);
  return (ua >> 16) | (ub & 0xFFFF0000u);
}
__device__ inline u16 f2bf(float a){
  u32 ua = __float_as_uint(a); ua += 0x7FFFu + ((ua >> 16) & 1u); return (u16)(ua >> 16);
}

// ---------- fp8 (OCP e4m3) helpers: 4 channels per u32 ----------
__device__ inline void acc_fp8(u32 s, float& a0, float& a1, float& a2, float& a3){
  f32x2 lo = __builtin_amdgcn_cvt_pk_f32_fp8((int)s, false);
  f32x2 hi = __builtin_amdgcn_cvt_pk_f32_fp8((int)s, true);
  a0 += lo.x; a1 += lo.y; a2 += hi.x; a3 += hi.y;
}
__device__ inline u32 pack_fp8(float a0, float a1, float a2, float a3){
  int o = __builtin_amdgcn_cvt_pk_fp8_f32(a0, a1, 0, false);
  o = __builtin_amdgcn_cvt_pk_fp8_f32(a2, a3, o, true);
  return (u32)o;
}

// ---------- CSR build ----------
__global__ void k_init(int* cnt, int n){
  int v = blockIdx.x * blockDim.x + threadIdx.x;
  if (v < n) cnt[v] = 0;
}
// count AND record each edge's rank within its dst bucket (coalesced store)
__global__ void k_count(const int* dst, int* cnt, int* rank, int e2){
  int j = blockIdx.x * blockDim.x + threadIdx.x;
  if (j < e2) rank[j] = atomicAdd(&cnt[dst[j]], 1);
}
// scan of PADDED counts: pc = (cnt+7)&~7  (rows padded to multiple of 8)
__global__ __launch_bounds__(256) void k_scan1(const int* cnt, int* partial, int* bsums, int n){
  __shared__ int lds[256];
  int t = threadIdx.x;
  int base = blockIdx.x * 1024 + t * 4;
  int v0=0,v1=0,v2=0,v3=0;
  if (base + 3 < n){ int4 q = *(const int4*)(cnt + base); v0=q.x; v1=q.y; v2=q.z; v3=q.w; }
  else {
    if (base + 0 < n) v0 = cnt[base];
    if (base + 1 < n) v1 = cnt[base+1];
    if (base + 2 < n) v2 = cnt[base+2];
  }
  v0 = (v0 + 7) & ~7; v1 = (v1 + 7) & ~7; v2 = (v2 + 7) & ~7; v3 = (v3 + 7) & ~7;
  v1 += v0; v2 += v1; v3 += v2;
  lds[t] = v3; __syncthreads();
  for (int off = 1; off < 256; off <<= 1){
    int x = (t >= off) ? lds[t - off] : 0;
    __syncthreads();
    lds[t] += x;
    __syncthreads();
  }
  int add = (t > 0) ? lds[t - 1] : 0;
  if (base + 3 < n){
    int4 q; q.x = v0+add; q.y = v1+add; q.z = v2+add; q.w = v3+add;
    *(int4*)(partial + base) = q;
  } else {
    if (base + 0 < n) partial[base]   = v0 + add;
    if (base + 1 < n) partial[base+1] = v1 + add;
    if (base + 2 < n) partial[base+2] = v2 + add;
  }
  if (t == 255) bsums[blockIdx.x] = lds[255];
}
__global__ void k_scan2(const int* bsums, int* bexc, int nb){
  __shared__ int lds[128];
  int t = threadIdx.x;
  lds[t] = (t < nb) ? bsums[t] : 0;
  __syncthreads();
  for (int off = 1; off < 128; off <<= 1){
    int x = (t >= off) ? lds[t - off] : 0;
    __syncthreads();
    lds[t] += x;
    __syncthreads();
  }
  if (t < nb) bexc[t] = (t > 0) ? lds[t - 1] : 0;
}
__global__ void k_scan3(const int* partial, const int* bexc, int* row_ptr, int n){
  int i = blockIdx.x * blockDim.x + threadIdx.x;
  if (i < n) row_ptr[i + 1] = partial[i] + bexc[i >> 10];
  if (i == 0) row_ptr[0] = 0;
}
__global__ void k_prep(const int* cnt, float* dinv, float* degf, int n){
  int v = blockIdx.x * blockDim.x + threadIdx.x;
  if (v < n){
    float c = (float)(cnt[v] + 1);   // in-degree + self-loop
    dinv[v] = rsqrtf(c);
    degf[v] = c;
  }
}
// scatter WITHOUT atomic: pos = row_ptr[dst] + precomputed rank
__global__ void k_scatter(const int* src, const int* dst, const int* rank,
                          const int* row_ptr, int2* ce, int e2){
  int j = blockIdx.x * blockDim.x + threadIdx.x;
  if (j < e2){
    int d = dst[j];
    int pos = row_ptr[d] + rank[j];
    ce[pos] = make_int2(src[j], j);
  }
}
// fill CSR pad slots with {n, 0}; zero the fp8 gather tables' row n (32 u32 each)
__global__ void k_pad(const int* row_ptr, const int* cnt, int2* ce,
                      u32* xws_zrow, u32* h_zrow, int n){
  int v = blockIdx.x * blockDim.x + threadIdx.x;
  if (v < n){
    int s = row_ptr[v] + cnt[v], e = row_ptr[v + 1];
    for (int i = s; i < e; ++i) ce[i] = make_int2(n, 0);
  }
  if (blockIdx.x == 0 && threadIdx.x < 32){
    xws_zrow[threadIdx.x] = 0u;
    h_zrow[threadIdx.x] = 0u;
  }
}

// ---------- fold W_le@W_bot and biases into the h2 GEMM weight ----------
// PARALLEL version: one block per output row (160 blocks x 128 threads).
// Old single-block version was 72 us (0.02% occupancy, serial load chain).
__global__ __launch_bounds__(128) void k_wcombo(const float* W_lin, const float* b_lin,
                                                const float* W_le, const float* b_le, float* Wfull){
  int r = blockIdx.x, c = threadIdx.x;
  if (r < DH){
    Wfull[r * DH + c] = W_lin[r * DH + c];            // W_top copy
  } else if (r < DH + DE){
    int i = r - DH;                                   // combo row i = W_le[i,:] @ W_bot
    float acc = 0.f;
    #pragma unroll 8
    for (int k = 0; k < DH; k += 4){
      float4 wl = *(const float4*)(W_le + i * DH + k);   // broadcast
      acc += wl.x * W_lin[(size_t)(DH + k    ) * DH + c];
      acc += wl.y * W_lin[(size_t)(DH + k + 1) * DH + c];
      acc += wl.z * W_lin[(size_t)(DH + k + 2) * DH + c];
      acc += wl.w * W_lin[(size_t)(DH + k + 3) * DH + c];
    }
    Wfull[r * DH + c] = acc;
  } else if (r == 144){
    float acc = b_lin[c];                             // bias row: b_le @ W_bot + b_lin
    #pragma unroll 8
    for (int k = 0; k < DH; k += 4){
      float4 bl = *(const float4*)(b_le + k);
      acc += bl.x * W_lin[(size_t)(DH + k    ) * DH + c];
      acc += bl.y * W_lin[(size_t)(DH + k + 1) * DH + c];
      acc += bl.z * W_lin[(size_t)(DH + k + 2) * DH + c];
      acc += bl.w * W_lin[(size_t)(DH + k + 3) * DH + c];
    }
    Wfull[r * DH + c] = acc;
  } else {
    Wfull[r * DH + c] = 0.f;
  }
}

// ---------- MFMA GEMM: [M,K] @ [K,128] -> bf16 (stride 64 u32) or fp8 (stride 32 u32) ----------
template<int K, bool RELU, bool ABF16, bool SCALE, bool OFP8>
__global__ __launch_bounds__(256) void k_gemm_mfma(const void* Ap, const float* W, u32* outb,
                                                   const float* scale, int M){
  constexpr int SA = K + 8;      // u16 stride
  constexpr int CS = 136;        // Ct stride (u16)
  __shared__ u16 Wt[128 * SA];   // W transposed, bf16: Wt[c][k]
  __shared__ u16 At[64 * SA];    // A tile bf16 (reused as Ct in epilogue)
  int tid = threadIdx.x;
  int row0 = blockIdx.x * 64;

  // ---- stage Wt: coalesced fp32 reads, transposed bf16x8 LDS writes ----
  {
    int c = tid & 127, half = tid >> 7;
    for (int g = half; g < K / 8; g += 2){
      int k0 = g * 8;
      float w0 = W[(size_t)(k0+0)*128 + c], w1 = W[(size_t)(k0+1)*128 + c];
      float w2 = W[(size_t)(k0+2)*128 + c], w3 = W[(size_t)(k0+3)*128 + c];
      float w4 = W[(size_t)(k0+4)*128 + c], w5 = W[(size_t)(k0+5)*128 + c];
      float w6 = W[(size_t)(k0+6)*128 + c], w7 = W[(size_t)(k0+7)*128 + c];
      uint4 pk;
      pk.x = fpack2(w0, w1); pk.y = fpack2(w2, w3);
      pk.z = fpack2(w4, w5); pk.w = fpack2(w6, w7);
      *(uint4*)&Wt[c * SA + k0] = pk;
    }
  }
  // ---- stage At ----
  constexpr int CH = K / 8;
  for (int idx = tid; idx < 64 * CH; idx += 256){
    int r = idx / CH, ch = idx - r * CH;
    int gr = row0 + r; if (gr > M - 1) gr = M - 1;
    uint4 pk;
    if (ABF16){
      pk = *(const uint4*)((const u16*)Ap + (size_t)gr * K + ch * 8);
    } else {
      const float* A = (const float*)Ap + (size_t)gr * K + ch * 8;
      float4 q0 = *(const float4*)A;
      float4 q1 = *(const float4*)(A + 4);
      pk.x = fpack2(q0.x, q0.y); pk.y = fpack2(q0.z, q0.w);
      pk.z = fpack2(q1.x, q1.y); pk.w = fpack2(q1.z, q1.w);
    }
    *(uint4*)&At[r * SA + ch * 8] = pk;
  }
  __syncthreads();

  // ---- MFMA main loop ----
  int l = tid & 63, w = tid >> 6;
  int m = l & 15, quad = l >> 4;
  f32x4 acc[8];
  #pragma unroll
  for (int ct = 0; ct < 8; ++ct) acc[ct] = (f32x4){0.f, 0.f, 0.f, 0.f};
  #pragma unroll
  for (int ks = 0; ks < K; ks += 32){
    short8 av = *(const short8*)&At[(w * 16 + m) * SA + ks + quad * 8];
    #pragma unroll
    for (int ct = 0; ct < 8; ++ct){
      short8 bv = *(const short8*)&Wt[(ct * 16 + m) * SA + ks + quad * 8];
      acc[ct] = __builtin_amdgcn_mfma_f32_16x16x32_bf16(av, bv, acc[ct], 0, 0, 0);
    }
  }
  __syncthreads();   // done reading At — reuse as Ct

  // ---- epilogue: scale/relu, bf16 pack into Ct ----
  u16* Ct = At;
  float sc[4];
  if (SCALE){
    #pragma unroll
    for (int r = 0; r < 4; ++r){
      int gr = row0 + w * 16 + quad * 4 + r;
      sc[r] = scale[gr < M ? gr : (M - 1)];
    }
  }
  #pragma unroll
  for (int ct = 0; ct < 8; ++ct){
    #pragma unroll
    for (int r = 0; r < 4; ++r){
      float vv = acc[ct][r];
      if (SCALE) vv *= sc[r];
      if (RELU)  vv = fmaxf(vv, 0.f);
      Ct[(w * 16 + quad * 4 + r) * CS + ct * 16 + m] = f2bf(vv);
    }
  }
  __syncthreads();
  if (OFP8){
    // convert bf16 Ct -> fp8 rows (128 B), coalesced uint2 stores
    for (int idx = tid; idx < 64 * 16; idx += 256){
      int r = idx >> 4, c8 = idx & 15;
      int gr = row0 + r;
      if (gr < M){
        uint4 qv = *(const uint4*)&Ct[r * CS + c8 * 8];
        uint2 ov;
        ov.x = (u32)__builtin_amdgcn_cvt_pk_fp8_f32(bf_lo(qv.y), bf_hi(qv.y),
               __builtin_amdgcn_cvt_pk_fp8_f32(bf_lo(qv.x), bf_hi(qv.x), 0, false), true);
        ov.y = (u32)__builtin_amdgcn_cvt_pk_fp8_f32(bf_lo(qv.w), bf_hi(qv.w),
               __builtin_amdgcn_cvt_pk_fp8_f32(bf_lo(qv.z), bf_hi(qv.z), 0, false), true);
        *(uint2*)(outb + (size_t)gr * 32 + c8 * 2) = ov;
      }
    }
  } else {
    for (int idx = tid; idx < 64 * 16; idx += 256){
      int r = idx >> 4, ch = idx & 15;
      int gr = row0 + r;
      if (gr < M){
        uint4 q = *(const uint4*)&Ct[r * CS + ch * 8];
        *(uint4*)(outb + (size_t)gr * 64 + ch * 4) = q;
      }
    }
  }
}

// ---------- phase 1: fp8 table, 2 nodes/wave, software-pipelined 16-deep gathers ----------
__global__ __launch_bounds__(256) void k_phase1(const u32* xws8, const int* row_ptr, const int2* ce,
                                                const float* dinv, const float* b_gcn, u32* h8, int n){
  int lane = threadIdx.x & 63;
  int ln = lane & 31;
  int v = blockIdx.x * 8 + ((threadIdx.x >> 6) << 1) + (lane >> 5);
  if (v >= n) return;
  u32 sp = xws8[(size_t)v * 32 + ln];
  float a0 = 0.f, a1 = 0.f, a2 = 0.f, a3 = 0.f;
  acc_fp8(sp, a0, a1, a2, a3);
  int e0 = row_ptr[v], e1 = row_ptr[v + 1];
  int i = e0;
  u32 q0=0,q1=0,q2=0,q3=0,q4=0,q5=0,q6=0,q7=0;
  if (i < e1){
    const int4* cp = (const int4*)(ce + i);
    int4 A = cp[0], B = cp[1], C = cp[2], D = cp[3];
    q0 = xws8[(size_t)A.x * 32 + ln]; q1 = xws8[(size_t)A.z * 32 + ln];
    q2 = xws8[(size_t)B.x * 32 + ln]; q3 = xws8[(size_t)B.z * 32 + ln];
    q4 = xws8[(size_t)C.x * 32 + ln]; q5 = xws8[(size_t)C.z * 32 + ln];
    q6 = xws8[(size_t)D.x * 32 + ln]; q7 = xws8[(size_t)D.z * 32 + ln];
  }
  for (; i + 8 < e1; i += 8){
    const int4* cp2 = (const int4*)(ce + i + 8);
    int4 A = cp2[0], B = cp2[1], C = cp2[2], D = cp2[3];
    u32 p0 = xws8[(size_t)A.x * 32 + ln], p1 = xws8[(size_t)A.z * 32 + ln];
    u32 p2 = xws8[(size_t)B.x * 32 + ln], p3 = xws8[(size_t)B.z * 32 + ln];
    u32 p4 = xws8[(size_t)C.x * 32 + ln], p5 = xws8[(size_t)C.z * 32 + ln];
    u32 p6 = xws8[(size_t)D.x * 32 + ln], p7 = xws8[(size_t)D.z * 32 + ln];
    acc_fp8(q0, a0, a1, a2, a3); acc_fp8(q1, a0, a1, a2, a3);
    acc_fp8(q2, a0, a1, a2, a3); acc_fp8(q3, a0, a1, a2, a3);
    acc_fp8(q4, a0, a1, a2, a3); acc_fp8(q5, a0, a1, a2, a3);
    acc_fp8(q6, a0, a1, a2, a3); acc_fp8(q7, a0, a1, a2, a3);
    q0=p0; q1=p1; q2=p2; q3=p3; q4=p4; q5=p5; q6=p6; q7=p7;
  }
  if (i < e1){
    acc_fp8(q0, a0, a1, a2, a3); acc_fp8(q1, a0, a1, a2, a3);
    acc_fp8(q2, a0, a1, a2, a3); acc_fp8(q3, a0, a1, a2, a3);
    acc_fp8(q4, a0, a1, a2, a3); acc_fp8(q5, a0, a1, a2, a3);
    acc_fp8(q6, a0, a1, a2, a3); acc_fp8(q7, a0, a1, a2, a3);
  }
  float dv = dinv[v];
  float4 bg = *(const float4*)(b_gcn + ln * 4);
  a0 = fmaxf(fmaf(dv, a0, bg.x), 0.f);
  a1 = fmaxf(fmaf(dv, a1, bg.y), 0.f);
  a2 = fmaxf(fmaf(dv, a2, bg.z), 0.f);
  a3 = fmaxf(fmaf(dv, a3, bg.w), 0.f);
  h8[(size_t)v * 32 + ln] = pack_fp8(a0, a1, a2, a3);
}

// ---------- phase 2: fp8 h-table, pipelined; ea gather via cndmask-selected slots ----------
__global__ __launch_bounds__(256) void k_phase2(const u32* h8, const int* row_ptr, const int2* ce,
                                                const float* edge_attr, const float* degf,
                                                u16* A2b, int n){
  int lane = threadIdx.x & 63;
  int ln = lane & 31;
  int half = lane >> 5;
  int v = blockIdx.x * 8 + ((threadIdx.x >> 6) << 1) + half;
  if (v >= n) return;
  u32 sp = h8[(size_t)v * 32 + ln];
  float a0 = 0.f, a1 = 0.f, a2 = 0.f, a3 = 0.f;
  acc_fp8(sp, a0, a1, a2, a3);
  float es = 0.f;                  // channel ln&15, slot-group ln>>4 (4 edges each)
  int ch = ln & 15, grp = ln >> 4;
  int e0 = row_ptr[v], e1 = row_ptr[v + 1];
  int i = e0;
  u32 q0=0,q1=0,q2=0,q3=0,q4=0,q5=0,q6=0,q7=0;
  int4 A = {0,0,0,0}, B = {0,0,0,0}, C = {0,0,0,0}, D = {0,0,0,0};
  if (i < e1){
    const int4* cp = (const int4*)(ce + i);
    A = cp[0]; B = cp[1]; C = cp[2]; D = cp[3];
    q0 = h8[(size_t)A.x * 32 + ln]; q1 = h8[(size_t)A.z * 32 + ln];
    q2 = h8[(size_t)B.x * 32 + ln]; q3 = h8[(size_t)B.z * 32 + ln];
    q4 = h8[(size_t)C.x * 32 + ln]; q5 = h8[(size_t)C.z * 32 + ln];
    q6 = h8[(size_t)D.x * 32 + ln]; q7 = h8[(size_t)D.z * 32 + ln];
  }
  for (; i + 8 < e1; i += 8){
    const int4* cp2 = (const int4*)(ce + i + 8);
    int4 A2 = cp2[0], B2 = cp2[1], C2 = cp2[2], D2 = cp2[3];
    // ea slots for CURRENT block from regs (grp 0 -> A,B; grp 1 -> C,D)
    int s0x = grp ? C.x : A.x, s0y = grp ? C.y : A.y;
    int s1x = grp ? C.z : A.z, s1y = grp ? C.w : A.w;
    int s2x = grp ? D.x : B.x, s2y = grp ? D.y : B.y;
    int s3x = grp ? D.z : B.z, s3y = grp ? D.w : B.w;
    float v0 = edge_attr[(size_t)(s0y >> 1) * DE + ch];
    float v1 = edge_attr[(size_t)(s1y >> 1) * DE + ch];
    float v2 = edge_attr[(size_t)(s2y >> 1) * DE + ch];
    float v3 = edge_attr[(size_t)(s3y >> 1) * DE + ch];
    // next block's gathers
    u32 p0 = h8[(size_t)A2.x * 32 + ln], p1 = h8[(size_t)A2.z * 32 + ln];
    u32 p2 = h8[(size_t)B2.x * 32 + ln], p3 = h8[(size_t)B2.z * 32 + ln];
    u32 p4 = h8[(size_t)C2.x * 32 + ln], p5 = h8[(size_t)C2.z * 32 + ln];
    u32 p6 = h8[(size_t)D2.x * 32 + ln], p7 = h8[(size_t)D2.z * 32 + ln];
    // consume current
    acc_fp8(q0, a0, a1, a2, a3); acc_fp8(q1, a0, a1, a2, a3);
    acc_fp8(q2, a0, a1, a2, a3); acc_fp8(q3, a0, a1, a2, a3);
    acc_fp8(q4, a0, a1, a2, a3); acc_fp8(q5, a0, a1, a2, a3);
    acc_fp8(q6, a0, a1, a2, a3); acc_fp8(q7, a0, a1, a2, a3);
    es = fmaf((s0x != n) ? 1.f : 0.f, v0, es);
    es = fmaf((s1x != n) ? 1.f : 0.f, v1, es);
    es = fmaf((s2x != n) ? 1.f : 0.f, v2, es);
    es = fmaf((s3x != n) ? 1.f : 0.f, v3, es);
    q0=p0; q1=p1; q2=p2; q3=p3; q4=p4; q5=p5; q6=p6; q7=p7;
    A=A2; B=B2; C=C2; D=D2;
  }
  if (i < e1){
    int s0x = grp ? C.x : A.x, s0y = grp ? C.y : A.y;
    int s1x = grp ? C.z : A.z, s1y = grp ? C.w : A.w;
    int s2x = grp ? D.x : B.x, s2y = grp ? D.y : B.y;
    int s3x = grp ? D.z : B.z, s3y = grp ? D.w : B.w;
    float v0 = edge_attr[(size_t)(s0y >> 1) * DE + ch];
    float v1 = edge_attr[(size_t)(s1y >> 1) * DE + ch];
    float v2 = edge_attr[(size_t)(s2y >> 1) * DE + ch];
    float v3 = edge_attr[(size_t)(s3y >> 1) * DE + ch];
    acc_fp8(q0, a0, a1, a2, a3); acc_fp8(q1, a0, a1, a2, a3);
    acc_fp8(q2, a0, a1, a2, a3); acc_fp8(q3, a0, a1, a2, a3);
    acc_fp8(q4, a0, a1, a2, a3); acc_fp8(q5, a0, a1, a2, a3);
    acc_fp8(q6, a0, a1, a2, a3); acc_fp8(q7, a0, a1, a2, a3);
    es = fmaf((s0x != n) ? 1.f : 0.f, v0, es);
    es = fmaf((s1x != n) ? 1.f : 0.f, v1, es);
    es = fmaf((s2x != n) ? 1.f : 0.f, v2, es);
    es = fmaf((s3x != n) ? 1.f : 0.f, v3, es);
  }
  // within-half reduction over the 2 slot groups, then wave-uniform pair pick
  es += __shfl_xor(es, 16);
  float c0v = __shfl(es, half * 32 + (ln & 7) * 2);
  float c1v = __shfl(es, half * 32 + (ln & 7) * 2 + 1);
  u32* rowp = (u32*)(A2b + (size_t)v * 160);
  uint2 o; o.x = fpack2(a0, a1); o.y = fpack2(a2, a3);
  *(uint2*)(rowp + ln * 2) = o;
  if (ln < 8){
    rowp[64 + ln] = fpack2(c0v + 1.0f, c1v + 1.0f);
  } else if (ln < 16){
    rowp[64 + ln] = (ln == 8) ? (u32)f2bf(degf[v]) : 0u;
  }
}

// ---------- pooling ----------
__global__ void k_starts(const int* batch, int* start, int n, int g){
  int v = blockIdx.x * blockDim.x + threadIdx.x;
  if (v >= n) return;
  int b = batch[v];
  int prev = (v == 0) ? -1 : batch[v - 1];
  for (int q = prev + 1; q <= b; ++q) start[q] = v;
  if (v == n - 1){ for (int q = b + 1; q <= g; ++q) start[q] = n; }
}
// stage A: (graph, sub) blocks; 32 sub-blocks per graph for occupancy
__global__ __launch_bounds__(256) void k_pool_a(const u32* h2_b, const int* start, float* partialp){
  __shared__ float2 red[256];
  int g = blockIdx.x >> 5;
  int s = blockIdx.x & (PSUB - 1);
  int s0 = start[g], s1 = start[g + 1];
  int tid = threadIdx.x;
  int cu = tid & 63, rr = tid >> 6;
  float ax = 0.f, ay = 0.f;
  for (int r = s0 + s * 4 + rr; r < s1; r += PSUB * 4){
    u32 q = h2_b[(size_t)r * 64 + cu];
    ax += bf_lo(q); ay += bf_hi(q);
  }
  red[tid] = make_float2(ax, ay);
  __syncthreads();
  if (rr == 0){
    #pragma unroll
    for (int p = 1; p < 4; p++){ float2 o = red[cu + (p << 6)]; ax += o.x; ay += o.y; }
    *(float2*)(partialp + (size_t)blockIdx.x * 128 + cu * 2) = make_float2(ax, ay);
  }
}
// stage B fused with final linear: reduce 32 partials, mean, @ W_out + b_out
__global__ __launch_bounds__(128) void k_poolb_final(const float* partialp, const int* start,
                                                     const float* W_out, const float* b_out,
                                                     float* out){
  __shared__ float pl[DH];
  int g = blockIdx.x, c = threadIdx.x;
  float sum = 0.f;
  #pragma unroll 4
  for (int s = 0; s < PSUB; ++s) sum += partialp[((size_t)g * PSUB + s) * 128 + c];
  int cntg = start[g + 1] - start[g]; if (cntg < 1) cntg = 1;
  pl[c] = sum / (float)cntg;
  __syncthreads();
  float acc = b_out[c];
  for (int k = 0; k < DH; ++k) acc += pl[k] * W_out[k * DO + c];
  out[g * DO + c] = acc;
}

extern "C" void kernel_launch(void* const* d_in, const int* in_sizes, int n_in,
                              void* d_out, int out_size, void* d_ws, size_t ws_size,
                              hipStream_t stream){
  const float* x         = (const float*)d_in[0];
  const int*   edge_index= (const int*)  d_in[1];
  const float* edge_attr = (const float*)d_in[2];
  const int*   batch     = (const int*)  d_in[3];
  const float* W_gcn     = (const float*)d_in[4];
  const float* b_gcn     = (const float*)d_in[5];
  const float* W_le      = (const float*)d_in[6];
  const float* b_le      = (const float*)d_in[7];
  const float* W_lin     = (const float*)d_in[8];
  const float* b_lin     = (const float*)d_in[9];
  const float* W_out     = (const float*)d_in[10];
  const float* b_out     = (const float*)d_in[11];
  float* out = (float*)d_out;

  const int n  = in_sizes[0] / DV;       // 100000
  const int e2 = in_sizes[1] / 2;        // 1600000 directed edges
  const int g  = out_size / DO;          // 64
  const int* srcp = edge_index;
  const int* dstp = edge_index + e2;
  const int e2pad = e2 + 7 * n + 8;      // CSR capacity with per-row pad-to-8

  char* ws = (char*)d_ws;
  size_t off = 0;
  auto alloc = [&](size_t bytes) -> char* {
    char* p = ws + off; off = (off + bytes + 255) & ~(size_t)255; return p;
  };

  int*   cnt     = (int*)  alloc((size_t)n * 4);
  int*   row_ptr = (int*)  alloc((size_t)(n + 1) * 4);
  int*   rank    = (int*)  alloc((size_t)e2 * 4);
  int*   partial = (int*)  alloc((size_t)n * 4);
  int*   bsums   = (int*)  alloc(512);
  int*   bexc    = (int*)  alloc(512);
  float* dinv    = (float*)alloc((size_t)n * 4);
  float* degf    = (float*)alloc((size_t)n * 4);
  int*   startg  = (int*)  alloc((size_t)(g + 1) * 4);
  float* partialp= (float*)alloc((size_t)g * PSUB * 128 * 4);
  float* Wfull   = (float*)alloc(160 * DH * 4);
  u32*   h8      = (u32*)  alloc((size_t)(n + 1) * 128);   // fp8 rows, +1 zero row
  int2*  ce      = (int2*) alloc((size_t)e2pad * 8);
  u32*   h2_b    = (u32*)  alloc((size_t)n * 64 * 4);
  // region A: xws8 (fp8, [N+1,128B]) later overwritten by A2 (bf16, [N,160])
  size_t szXW = (size_t)(n + 1) * 128, szA2 = (size_t)n * 160 * 2;
  char* regionA = alloc(szA2 > szXW ? szA2 : szXW);
  u32* xws8 = (u32*)regionA;
  u16* A2b  = (u16*)regionA;

  const int nb1024 = (n + 1023) / 1024;  // must be <= 128 for k_scan2

  k_init   <<<(n + 255) / 256, 256, 0, stream>>>(cnt, n);
  k_count  <<<(e2 + 255) / 256, 256, 0, stream>>>(dstp, cnt, rank, e2);
  k_scan1  <<<nb1024, 256, 0, stream>>>(cnt, partial, bsums, n);
  k_scan2  <<<1, 128, 0, stream>>>(bsums, bexc, nb1024);
  k_scan3  <<<(n + 255) / 256, 256, 0, stream>>>(partial, bexc, row_ptr, n);
  k_prep   <<<(n + 255) / 256, 256, 0, stream>>>(cnt, dinv, degf, n);
  k_scatter<<<(e2 + 255) / 256, 256, 0, stream>>>(srcp, dstp, rank, row_ptr, ce, e2);
  k_pad    <<<(n + 255) / 256, 256, 0, stream>>>(row_ptr, cnt, ce,
                                                 xws8 + (size_t)n * 32, h8 + (size_t)n * 32, n);
  k_wcombo <<<160, 128, 0, stream>>>(W_lin, b_lin, W_le, b_le, Wfull);

  k_gemm_mfma<DV, false, false, true, true><<<(n + 63) / 64, 256, 0, stream>>>(x, W_gcn, xws8, dinv, n);
  k_phase1 <<<(n + 7) / 8, 256, 0, stream>>>(xws8, row_ptr, ce, dinv, b_gcn, h8, n);
  k_phase2 <<<(n + 7) / 8, 256, 0, stream>>>(h8, row_ptr, ce, edge_attr, degf, A2b, n);
  k_gemm_mfma<160, true, true, false, false><<<(n + 63) / 64, 256, 0, stream>>>(A2b, Wfull, h2_b, (const float*)nullptr, n);

  k_starts      <<<(n + 255) / 256, 256, 0, stream>>>(batch, startg, n, g);
  k_pool_a      <<<g * PSUB, 256, 0, stream>>>(h2_b, startg, partialp);
  k_poolb_final <<<g, 128, 0, stream>>>(partialp, startg, W_out, b_out, out);
}